// Round 6
// baseline (884.265 us; speedup 1.0000x reference)
//
#include <hip/hip_runtime.h>

// Problem constants
#define NATOMS 4096
#define NTYPES 2
#define NA 2048
#define MAXNB 100
#define JN 200          // neighbors per atom
#define TFD 4
#define E0 25           // emb hidden 0
#define E1 50           // emb hidden 1
#define GD 100          // GDIM
#define M2D 16
#define DD 1600         // D = M2*GDIM
#define FHD 240
#define INV200 (1.0f/200.0f)

// Output layout (floats): Etot@0 (1), Ei@1 (4096), F@4097 (12288), Virial@16385 (9)
#define OUT_EI 1
#define OUT_F 4097
#define OUT_V 16385

// Workspace layout (floats)
#define WS_DRQ 0L                 // 4096*1600  (dr, later overwritten by Q)
#define WS_XA 6553600L            // 4096*400
#define WS_P 8192000L             // 4096*400  (g-major float4: [n][g][c])
#define WS_FH0 9830400L           // 4096*240
#define WS_FH1 10813440L          // 4096*240
#define WS_DH0G 11796480L         // 4096*240
#define WS_FW0T 12779520L         // 2*240*1600

// G(s) lookup table. Embedding-net input is [s, temb(type)] with temb constant
// per type, so G is a 1-D function of s per type. Cubic Hermite, 2048 knots.
// Packed float4 per (type,knot,g): (G_i, dG_i, G_{i+1}, dG_{i+1}).
#define NK 2048
#define S_MIN (-8.0f)
#define S_H 0.0078125f      // 16/2048
#define S_INVH 128.0f
__device__ float4 g_tab4[NTYPES * NK * GD];
__device__ float2 g_th1[NTYPES * NK * E1];   // (h1, v1=dh1/ds) per (t,knot,l)

__device__ __forceinline__ float ftanh(float x) {
    float ax = fabsf(x);
    float e = __expf(-2.0f * ax);
    float t = (1.0f - e) / (1.0f + e);
    return copysignf(t, x);
}

// ---------------- setup: transpose fw0 ----------------
__global__ void k_setup(const float* __restrict__ fw0, float* __restrict__ fw0T) {
    int idx = blockIdx.x * 256 + threadIdx.x;
    if (idx < NTYPES * DD * FHD) {
        int t = idx / (DD * FHD);
        int r = idx % (DD * FHD);
        int o = r / DD, d = r % DD;
        fw0T[idx] = fw0[(long)t * DD * FHD + (long)d * FHD + o];
    }
}

// ---------------- table stage 1: h1/v1 per (type, knot) ----------------
__global__ __launch_bounds__(256) void k_table_h(
    const float* __restrict__ ew0, const float* __restrict__ eb0,
    const float* __restrict__ ew1, const float* __restrict__ eb1,
    const float* __restrict__ tv)
{
    int idx = blockIdx.x * 256 + threadIdx.x;
    if (idx >= NTYPES * NK) return;
    int t = idx / NK, i = idx % NK;
    float s = S_MIN + (float)i * S_H;

    float h0[E0], t0[E0];
#pragma unroll
    for (int k = 0; k < E0; ++k) {
        float c = eb0[k];
#pragma unroll
        for (int f = 0; f < TFD; ++f) c = fmaf(tv[t * TFD + f], ew0[(1 + f) * E0 + k], c);
        float h = ftanh(fmaf(s, ew0[k], c));
        h0[k] = h;
        t0[k] = (1.f - h * h) * ew0[k];
    }
#pragma unroll 2
    for (int l = 0; l < E1; ++l) {
        float acc = eb1[l], dacc = 0.f;
#pragma unroll
        for (int k = 0; k < E0; ++k) {
            float w = ew1[k * E1 + l];
            acc = fmaf(h0[k], w, acc);
            dacc = fmaf(t0[k], w, dacc);
        }
        float h = ftanh(acc);
        g_th1[(long)idx * E1 + l] = make_float2(h, (1.f - h * h) * dacc);
    }
}

// ---------------- table stage 2: one thread per (type, knot, g) ----------------
__global__ __launch_bounds__(256) void k_table_g(
    const float* __restrict__ ew2, const float* __restrict__ eb2)
{
    long idx = (long)blockIdx.x * 256 + threadIdx.x;
    if (idx >= (long)NTYPES * NK * GD) return;
    int g = idx % GD;
    long ti = idx / GD;          // t*NK + i
    int i = ti % NK;

    const float2* hv = g_th1 + ti * E1;
    float acc = eb2[g], dacc = 0.f;
#pragma unroll 5
    for (int l = 0; l < E1; ++l) {
        float2 x = hv[l];
        float w = ew2[l * GD + g];
        acc = fmaf(x.x, w, acc);
        dacc = fmaf(x.y, w, dacc);
    }
    float G = ftanh(acc);
    float dv = (1.f - G * G) * dacc;

    float2* f2 = (float2*)g_tab4;
    long e = ti * GD + g;
    f2[2 * e] = make_float2(G, dv);                        // (x,y) of entry i
    if (i > 0) f2[2 * (e - GD) + 1] = make_float2(G, dv);  // (z,w) of entry i-1
}

// Hermite basis; returns row pointer into packed table for (tau, knot i).
__device__ __forceinline__ const float4* hermite4(float s, int tau,
    float& c00, float& c01, float& c10, float& c11,
    float& d00, float& d10, float& d11)
{
    float x = (s - S_MIN) * S_INVH;
    x = fminf(fmaxf(x, 0.f), (float)(NK - 1) - 1e-3f);
    int i = (int)x;
    float u = x - (float)i;
    float um = 1.f - u;
    c00 = (1.f + 2.f * u) * um * um;
    c01 = u * u * (3.f - 2.f * u);
    c10 = S_H * u * um * um;
    c11 = S_H * u * u * (u - 1.f);
    d00 = (6.f * u * u - 6.f * u) * S_INVH;
    d10 = fmaf(3.f * u, u, fmaf(-4.f, u, 1.f));
    d11 = fmaf(3.f * u, u, -2.f * u);
    return g_tab4 + (long)(tau * NK + i) * GD;
}

// ---------------- K1: per-atom G (table) -> xa -> dr ----------------
#define GCH 25
__global__ __launch_bounds__(256) void k1_emb(
    const float* __restrict__ Ri,
    float* __restrict__ dr_ws, float* __restrict__ xa_ws)
{
    __shared__ float a4s[JN * 4];
    __shared__ float Gs[GCH * 201];
    __shared__ float xas[4 * GD];
    __shared__ float red[256];

    int tid = threadIdx.x;
    int n = blockIdx.x;

    float4 a = make_float4(0.f, 0.f, 0.f, 0.f);
    const float4* row = nullptr;
    float c00 = 0.f, c01 = 0.f, c10 = 0.f, c11 = 0.f, d00, d10, d11;
    if (tid < JN) {
        a = ((const float4*)Ri)[(long)n * JN + tid];
        ((float4*)a4s)[tid] = a;
        row = hermite4(a.x, tid / MAXNB, c00, c01, c10, c11, d00, d10, d11);
    }
    __syncthreads();

    int gl_r = tid % GCH;
    int c_r = (tid / GCH) % 4;
    int jh_r = tid / 100;

    for (int cc = 0; cc < 4; ++cc) {
        int g0 = cc * GCH;
        if (tid < JN) {
#pragma unroll
            for (int gl = 0; gl < GCH; ++gl) {
                float4 r = row[g0 + gl];
                Gs[gl * 201 + tid] = r.x * c00 + r.z * c01 + r.y * c10 + r.w * c11;
            }
        }
        __syncthreads();
        float s_ = 0.f;
        if (tid < JN) {
            const float* grow = &Gs[gl_r * 201 + jh_r * 100];
            const float* arow = &a4s[jh_r * 400 + c_r];
            for (int jj = 0; jj < 100; ++jj)
                s_ = fmaf(arow[jj * 4], grow[jj], s_);
        }
        red[tid] = s_;
        __syncthreads();
        if (tid < 100) {
            int c = tid / GCH, gl = tid % GCH;
            xas[c * GD + g0 + gl] = (red[tid] + red[tid + 100]) * INV200;
        }
        __syncthreads();
    }

    for (int i = tid; i < 4 * GD; i += 256) xa_ws[(long)n * 400 + i] = xas[i];
    for (int i = tid; i < DD; i += 256) {
        int gg = i / M2D, m = i % M2D;
        float v = 0.f;
#pragma unroll
        for (int c = 0; c < 4; ++c) v = fmaf(xas[c * GD + gg], xas[c * GD + m], v);
        dr_ws[(long)n * DD + i] = v;
    }
}

// ---------------- generic tiled fp32 GEMM: C = act(A@B + bias), per-type batch z ----------------
__global__ __launch_bounds__(256) void gemm_kernel(
    const float* __restrict__ Ab, const float* __restrict__ Bb,
    const float* __restrict__ biasb, float* __restrict__ Cb,
    int M, int Nn, int K, long sA, long sB, long sBias, long sC, int do_tanh)
{
    int t = blockIdx.z;
    const float* A = Ab + (long)t * sA;
    const float* B = Bb + (long)t * sB;
    const float* bias = biasb ? (biasb + (long)t * sBias) : nullptr;
    float* C = Cb + (long)t * sC;

    __shared__ float As[16 * 64];
    __shared__ float Bs[16 * 64];

    int tid = threadIdx.x;
    int n0 = blockIdx.x * 64;
    int m0 = blockIdx.y * 64;
    int tx = tid % 16, ty = tid / 16;

    float acc[4][4];
#pragma unroll
    for (int i = 0; i < 4; ++i)
#pragma unroll
        for (int j = 0; j < 4; ++j) acc[i][j] = 0.f;

    int a_m = tid / 4;
    int a_k = (tid % 4) * 4;
    int b_k = tid / 16;
    int b_n = (tid % 16) * 4;

    for (int k0 = 0; k0 < K; k0 += 16) {
        float4 av = *(const float4*)&A[(long)(m0 + a_m) * K + k0 + a_k];
        float4 bv = make_float4(0.f, 0.f, 0.f, 0.f);
        if (n0 + b_n < Nn) bv = *(const float4*)&B[(long)(k0 + b_k) * Nn + n0 + b_n];
        __syncthreads();
        As[(a_k + 0) * 64 + a_m] = av.x;
        As[(a_k + 1) * 64 + a_m] = av.y;
        As[(a_k + 2) * 64 + a_m] = av.z;
        As[(a_k + 3) * 64 + a_m] = av.w;
        *(float4*)&Bs[b_k * 64 + b_n] = bv;
        __syncthreads();
#pragma unroll
        for (int k = 0; k < 16; ++k) {
            float4 a4v = *(const float4*)&As[k * 64 + ty * 4];
            float4 b4v = *(const float4*)&Bs[k * 64 + tx * 4];
            acc[0][0] = fmaf(a4v.x, b4v.x, acc[0][0]);
            acc[0][1] = fmaf(a4v.x, b4v.y, acc[0][1]);
            acc[0][2] = fmaf(a4v.x, b4v.z, acc[0][2]);
            acc[0][3] = fmaf(a4v.x, b4v.w, acc[0][3]);
            acc[1][0] = fmaf(a4v.y, b4v.x, acc[1][0]);
            acc[1][1] = fmaf(a4v.y, b4v.y, acc[1][1]);
            acc[1][2] = fmaf(a4v.y, b4v.z, acc[1][2]);
            acc[1][3] = fmaf(a4v.y, b4v.w, acc[1][3]);
            acc[2][0] = fmaf(a4v.z, b4v.x, acc[2][0]);
            acc[2][1] = fmaf(a4v.z, b4v.y, acc[2][1]);
            acc[2][2] = fmaf(a4v.z, b4v.z, acc[2][2]);
            acc[2][3] = fmaf(a4v.z, b4v.w, acc[2][3]);
            acc[3][0] = fmaf(a4v.w, b4v.x, acc[3][0]);
            acc[3][1] = fmaf(a4v.w, b4v.y, acc[3][1]);
            acc[3][2] = fmaf(a4v.w, b4v.z, acc[3][2]);
            acc[3][3] = fmaf(a4v.w, b4v.w, acc[3][3]);
        }
    }
#pragma unroll
    for (int i = 0; i < 4; ++i) {
        int mm = m0 + ty * 4 + i;
#pragma unroll
        for (int j = 0; j < 4; ++j) {
            int nn = n0 + tx * 4 + j;
            if (nn < Nn) {
                float v = acc[i][j];
                if (bias) v += bias[nn];
                if (do_tanh) v = ftanh(v);
                C[(long)mm * Nn + nn] = v;
            }
        }
    }
}

// ---------------- K3a: per-atom Ei + Etot + dh0g ----------------
__global__ __launch_bounds__(256) void k3a(
    const float* __restrict__ fh0, const float* __restrict__ fh1,
    const float* __restrict__ fw1, const float* __restrict__ fw2, const float* __restrict__ fb2,
    float* __restrict__ out, float* __restrict__ dh0g)
{
    int n = blockIdx.x;
    int t = n / NA;
    int tid = threadIdx.x;
    __shared__ float u1s[FHD];
    __shared__ float red[256];

    float p = 0.f;
    if (tid < FHD) {
        float h1v = fh1[(long)n * FHD + tid];
        float w2v = fw2[t * FHD + tid];
        p = h1v * w2v;
        u1s[tid] = w2v * (1.f - h1v * h1v);
    }
    red[tid] = p;
    __syncthreads();
    for (int off = 128; off > 0; off >>= 1) {
        if (tid < off) red[tid] += red[tid + off];
        __syncthreads();
    }
    if (tid == 0) {
        float e = red[0] + fb2[t];
        out[OUT_EI + n] = e;
        atomicAdd(out, e);
    }
    if (tid < FHD) {
        const float* w1row = fw1 + (long)t * FHD * FHD + (long)tid * FHD;
        float acc = 0.f;
        for (int o = 0; o < FHD; ++o) acc = fmaf(u1s[o], w1row[o], acc);
        float h0v = fh0[(long)n * FHD + tid];
        dh0g[(long)n * FHD + tid] = acc * (1.f - h0v * h0v);
    }
}

// ---------------- K3b: per-atom P, g-major float4 [n][g][c] (INV200 folded) ----------------
__global__ __launch_bounds__(256) void k3b(
    const float* __restrict__ Q, const float* __restrict__ xa, float* __restrict__ P4)
{
    int n = blockIdx.x;
    int tid = threadIdx.x;
    __shared__ float qs[DD];
    __shared__ float xs[400];
    for (int i = tid; i < DD; i += 256) qs[i] = Q[(long)n * DD + i];
    for (int i = tid; i < 400; i += 256) xs[i] = xa[(long)n * 400 + i];
    __syncthreads();
    for (int i = tid; i < 400; i += 256) {
        int c = i / GD, g = i % GD;
        float acc = 0.f;
        for (int m = 0; m < M2D; ++m) acc = fmaf(qs[g * M2D + m], xs[c * GD + m], acc);
        if (g < M2D) {
            for (int g2 = 0; g2 < GD; ++g2) acc = fmaf(qs[g2 * M2D + g], xs[c * GD + g2], acc);
        }
        P4[((long)n * GD + g) * 4 + c] = acc * INV200;
    }
}

// ---------------- K4: one block per atom, one WAVE per item ----------------
// Lane g owns channel g (g=lane, then g=64+lane for lane<36): the table-row read
// is a fully-coalesced 1600B load instead of a 64-line gather. g-reduction of
// 5 scalars (dEda0..3, ds) via __shfl_xor butterfly.
__global__ __launch_bounds__(256) void k4(
    const float* __restrict__ Ri, const float* __restrict__ dfeat,
    const float* __restrict__ ImageDR, const int* __restrict__ list_neigh,
    const float4* __restrict__ P4ws, float* __restrict__ out)
{
    __shared__ float4 a4s[JN];      // Ri rows for this atom
    __shared__ float4 Ps[GD];       // P4 for this atom
    __shared__ float res[JN * 5];   // per-item dEda0..3, ds
    __shared__ float facc3[3];
    __shared__ float vacc[6];

    int tid = threadIdx.x;
    int lane = tid & 63;
    int w = tid >> 6;
    int n = blockIdx.x;

    if (tid < JN) a4s[tid] = ((const float4*)Ri)[(long)n * JN + tid];
    if (tid < GD) Ps[tid] = P4ws[(long)n * GD + tid];
    if (tid < 3) facc3[tid] = 0.f;
    if (tid < 6) vacc[tid] = 0.f;
    __syncthreads();

    // each wave: 50 items; tau is wave-uniform (w<2 -> 0, w>=2 -> 1)
    for (int ii = 0; ii < 50; ++ii) {
        int j = w * 50 + ii;
        float4 a = a4s[j];          // same address across lanes -> LDS broadcast
        int tau = j / MAXNB;

        float c00, c01, c10, c11, d00, d10, d11;
        const float4* row = hermite4(a.x, tau, c00, c01, c10, c11, d00, d10, d11);

        float e0 = 0.f, e1 = 0.f, e2 = 0.f, e3 = 0.f, es = 0.f;
        {
            int g = lane;
            float4 r = row[g];      // coalesced: lanes 0..63 read 1KB contiguous
            float4 p = Ps[g];
            float G = r.x * c00 + r.z * c01 + r.y * c10 + r.w * c11;
            float dG = (r.x - r.z) * d00 + r.y * d10 + r.w * d11;
            float dEdG = p.x * a.x + p.y * a.y + p.z * a.z + p.w * a.w;
            e0 = fmaf(p.x, G, e0); e1 = fmaf(p.y, G, e1);
            e2 = fmaf(p.z, G, e2); e3 = fmaf(p.w, G, e3);
            es = fmaf(dEdG, dG, es);
        }
        if (lane < GD - 64) {
            int g = 64 + lane;
            float4 r = row[g];
            float4 p = Ps[g];
            float G = r.x * c00 + r.z * c01 + r.y * c10 + r.w * c11;
            float dG = (r.x - r.z) * d00 + r.y * d10 + r.w * d11;
            float dEdG = p.x * a.x + p.y * a.y + p.z * a.z + p.w * a.w;
            e0 = fmaf(p.x, G, e0); e1 = fmaf(p.y, G, e1);
            e2 = fmaf(p.z, G, e2); e3 = fmaf(p.w, G, e3);
            es = fmaf(dEdG, dG, es);
        }
#pragma unroll
        for (int mask = 32; mask > 0; mask >>= 1) {
            e0 += __shfl_xor(e0, mask);
            e1 += __shfl_xor(e1, mask);
            e2 += __shfl_xor(e2, mask);
            e3 += __shfl_xor(e3, mask);
            es += __shfl_xor(es, mask);
        }
        if (lane == 0) {
            res[j * 5 + 0] = e0 + es;   // ds folded into dEda0
            res[j * 5 + 1] = e1;
            res[j * 5 + 2] = e2;
            res[j * 5 + 3] = e3;
        }
    }
    __syncthreads();

    float v00 = 0.f, v01 = 0.f, v02 = 0.f, v11 = 0.f, v12 = 0.f, v22 = 0.f;
    if (tid < JN) {
        int j = tid;
        long item = (long)n * JN + j;
        float dEda0 = res[j * 5 + 0], dEda1 = res[j * 5 + 1];
        float dEda2 = res[j * 5 + 2], dEda3 = res[j * 5 + 3];

        const float4* dfp = (const float4*)(dfeat + item * 12);
        float4 q0 = dfp[0], q1 = dfp[1], q2 = dfp[2];
        float dEdx0 = dEda0 * q0.x + dEda1 * q0.w + dEda2 * q1.z + dEda3 * q2.y;
        float dEdx1 = dEda0 * q0.y + dEda1 * q1.x + dEda2 * q1.w + dEda3 * q2.z;
        float dEdx2 = dEda0 * q0.z + dEda1 * q1.y + dEda2 * q2.x + dEda3 * q2.w;

        atomicAdd(&facc3[0], dEdx0);
        atomicAdd(&facc3[1], dEdx1);
        atomicAdd(&facc3[2], dEdx2);

        int ln = list_neigh[item];
        if (ln > 0) {
            int ii2 = ln - 1;
            if (ii2 > NATOMS - 1) ii2 = NATOMS - 1;
            atomicAdd(&out[OUT_F + ii2 * 3 + 0], dEdx0);
            atomicAdd(&out[OUT_F + ii2 * 3 + 1], dEdx1);
            atomicAdd(&out[OUT_F + ii2 * 3 + 2], dEdx2);
            const float* im = ImageDR + item * 3;
            v00 = im[0] * dEdx0; v01 = im[0] * dEdx1; v02 = im[0] * dEdx2;
            v11 = im[1] * dEdx1; v12 = im[1] * dEdx2; v22 = im[2] * dEdx2;
        }
    }

#pragma unroll
    for (int mask = 32; mask > 0; mask >>= 1) {
        v00 += __shfl_xor(v00, mask);
        v01 += __shfl_xor(v01, mask);
        v02 += __shfl_xor(v02, mask);
        v11 += __shfl_xor(v11, mask);
        v12 += __shfl_xor(v12, mask);
        v22 += __shfl_xor(v22, mask);
    }
    if (lane == 0) {
        atomicAdd(&vacc[0], v00);
        atomicAdd(&vacc[1], v01);
        atomicAdd(&vacc[2], v02);
        atomicAdd(&vacc[3], v11);
        atomicAdd(&vacc[4], v12);
        atomicAdd(&vacc[5], v22);
    }
    __syncthreads();
    if (tid < 3) atomicAdd(&out[OUT_F + n * 3 + tid], -facc3[tid]);
    if (tid < 9) {
        const int vmap[9] = {0, 1, 2, 1, 3, 4, 2, 4, 5};
        atomicAdd(&out[OUT_V + tid], vacc[vmap[tid]]);
    }
}

extern "C" void kernel_launch(void* const* d_in, const int* in_sizes, int n_in,
                              void* d_out, int out_size, void* d_ws, size_t ws_size,
                              hipStream_t stream) {
    const float* Ri = (const float*)d_in[0];
    const float* dfeat = (const float*)d_in[1];
    const float* ImageDR = (const float*)d_in[2];
    const float* tv = (const float*)d_in[3];
    const float* ew0 = (const float*)d_in[4];
    const float* eb0 = (const float*)d_in[5];
    const float* ew1 = (const float*)d_in[6];
    const float* eb1 = (const float*)d_in[7];
    const float* ew2 = (const float*)d_in[8];
    const float* eb2 = (const float*)d_in[9];
    const float* fw0 = (const float*)d_in[10];
    const float* fb0 = (const float*)d_in[11];
    const float* fw1 = (const float*)d_in[12];
    const float* fb1 = (const float*)d_in[13];
    const float* fw2 = (const float*)d_in[14];
    const float* fb2 = (const float*)d_in[15];
    const int* list_neigh = (const int*)d_in[16];

    float* out = (float*)d_out;
    float* ws = (float*)d_ws;
    float* drQ = ws + WS_DRQ;
    float* xa = ws + WS_XA;
    float* P = ws + WS_P;
    float* fh0 = ws + WS_FH0;
    float* fh1 = ws + WS_FH1;
    float* dh0g = ws + WS_DH0G;
    float* fw0T = ws + WS_FW0T;

    hipMemsetAsync(d_out, 0, (size_t)out_size * sizeof(float), stream);

    k_setup<<<(NTYPES * DD * FHD + 255) / 256, 256, 0, stream>>>(fw0, fw0T);
    k_table_h<<<(NTYPES * NK + 255) / 256, 256, 0, stream>>>(ew0, eb0, ew1, eb1, tv);
    k_table_g<<<(NTYPES * NK * GD + 255) / 256, 256, 0, stream>>>(ew2, eb2);

    k1_emb<<<NATOMS, 256, 0, stream>>>(Ri, drQ, xa);

    // fit forward: fh0 = tanh(dr @ fw0 + fb0), fh1 = tanh(fh0 @ fw1 + fb1)
    gemm_kernel<<<dim3(4, 32, 2), 256, 0, stream>>>(drQ, fw0, fb0, fh0,
        2048, 240, 1600, 2048L * 1600, 1600L * 240, 240L, 2048L * 240, 1);
    gemm_kernel<<<dim3(4, 32, 2), 256, 0, stream>>>(fh0, fw1, fb1, fh1,
        2048, 240, 240, 2048L * 240, 240L * 240, 240L, 2048L * 240, 1);

    k3a<<<NATOMS, 256, 0, stream>>>(fh0, fh1, fw1, fw2, fb2, out, dh0g);

    // Q = dh0g @ fw0^T  (overwrites dr buffer)
    gemm_kernel<<<dim3(25, 32, 2), 256, 0, stream>>>(dh0g, fw0T, nullptr, drQ,
        2048, 1600, 240, 2048L * 240, 240L * 1600, 0L, 2048L * 1600, 0);

    k3b<<<NATOMS, 256, 0, stream>>>(drQ, xa, P);

    k4<<<NATOMS, 256, 0, stream>>>(Ri, dfeat, ImageDR, list_neigh,
        (const float4*)P, out);
}

// Round 7
// 709.296 us; speedup vs baseline: 1.2467x; 1.2467x over previous
//
#include <hip/hip_runtime.h>

// Problem constants
#define NATOMS 4096
#define NTYPES 2
#define NA 2048
#define MAXNB 100
#define JN 200          // neighbors per atom
#define TFD 4
#define E0 25           // emb hidden 0
#define E1 50           // emb hidden 1
#define GD 100          // GDIM
#define M2D 16
#define DD 1600         // D = M2*GDIM
#define FHD 240
#define INV200 (1.0f/200.0f)

// Output layout (floats): Etot@0 (1), Ei@1 (4096), F@4097 (12288), Virial@16385 (9)
#define OUT_EI 1
#define OUT_F 4097
#define OUT_V 16385

// Workspace layout (floats)
#define WS_DRQ 0L                 // 4096*1600  (dr, later overwritten by Q)
#define WS_XA 6553600L            // 4096*400
#define WS_P 8192000L             // 4096*400  (g-major float4: [n][g][c]); head doubles as fw1T before k3b
#define WS_FH0 9830400L           // 4096*240
#define WS_FH1 10813440L          // 4096*240
#define WS_DH0G 11796480L         // 4096*240
#define WS_FW0T 12779520L         // 2*240*1600
#define WS_FW1T WS_P              // 2*240*240, consumed by k3a BEFORE k3b writes P

// G(s) lookup table. Embedding-net input is [s, temb(type)] with temb constant
// per type, so G is a 1-D function of s per type. Cubic Hermite, 1024 knots
// (err ~2e-6; table 3.3MB -> fits one XCD L2). Packed float4 per (type,knot,g):
// (G_i, dG_i, G_{i+1}, dG_{i+1}).
#define NK 1024
#define S_MIN (-8.0f)
#define S_H 0.015625f       // 16/1024
#define S_INVH 64.0f
__device__ float4 g_tab4[NTYPES * NK * GD];
__device__ float2 g_th1[NTYPES * NK * E1];   // (h1, v1=dh1/ds) per (t,knot,l)

__device__ __forceinline__ float ftanh(float x) {
    float ax = fabsf(x);
    float e = __expf(-2.0f * ax);
    float t = (1.0f - e) / (1.0f + e);
    return copysignf(t, x);
}

// ---------------- setup: transpose fw0 (big) + fw1 (small) ----------------
__global__ void k_setup(const float* __restrict__ fw0, float* __restrict__ fw0T,
                        const float* __restrict__ fw1, float* __restrict__ fw1T) {
    int idx = blockIdx.x * 256 + threadIdx.x;
    if (idx < NTYPES * DD * FHD) {
        int t = idx / (DD * FHD);
        int r = idx % (DD * FHD);
        int o = r / DD, d = r % DD;
        fw0T[idx] = fw0[(long)t * DD * FHD + (long)d * FHD + o];
    }
    if (idx < NTYPES * FHD * FHD) {
        int t = idx / (FHD * FHD);
        int r = idx % (FHD * FHD);
        int o = r / FHD, i = r % FHD;
        fw1T[idx] = fw1[(long)t * FHD * FHD + (long)i * FHD + o];
    }
}

// ---------------- table stage 1: h1/v1 per (type, knot) ----------------
__global__ __launch_bounds__(256) void k_table_h(
    const float* __restrict__ ew0, const float* __restrict__ eb0,
    const float* __restrict__ ew1, const float* __restrict__ eb1,
    const float* __restrict__ tv)
{
    int idx = blockIdx.x * 256 + threadIdx.x;
    if (idx >= NTYPES * NK) return;
    int t = idx / NK, i = idx % NK;
    float s = S_MIN + (float)i * S_H;

    float h0[E0], t0[E0];
#pragma unroll
    for (int k = 0; k < E0; ++k) {
        float c = eb0[k];
#pragma unroll
        for (int f = 0; f < TFD; ++f) c = fmaf(tv[t * TFD + f], ew0[(1 + f) * E0 + k], c);
        float h = ftanh(fmaf(s, ew0[k], c));
        h0[k] = h;
        t0[k] = (1.f - h * h) * ew0[k];
    }
#pragma unroll 2
    for (int l = 0; l < E1; ++l) {
        float acc = eb1[l], dacc = 0.f;
#pragma unroll
        for (int k = 0; k < E0; ++k) {
            float w = ew1[k * E1 + l];
            acc = fmaf(h0[k], w, acc);
            dacc = fmaf(t0[k], w, dacc);
        }
        float h = ftanh(acc);
        g_th1[(long)idx * E1 + l] = make_float2(h, (1.f - h * h) * dacc);
    }
}

// ---------------- table stage 2: one thread per (type, knot, g) ----------------
__global__ __launch_bounds__(256) void k_table_g(
    const float* __restrict__ ew2, const float* __restrict__ eb2)
{
    long idx = (long)blockIdx.x * 256 + threadIdx.x;
    if (idx >= (long)NTYPES * NK * GD) return;
    int g = idx % GD;
    long ti = idx / GD;          // t*NK + i
    int i = ti % NK;

    const float2* hv = g_th1 + ti * E1;
    float acc = eb2[g], dacc = 0.f;
#pragma unroll 5
    for (int l = 0; l < E1; ++l) {
        float2 x = hv[l];
        float w = ew2[l * GD + g];
        acc = fmaf(x.x, w, acc);
        dacc = fmaf(x.y, w, dacc);
    }
    float G = ftanh(acc);
    float dv = (1.f - G * G) * dacc;

    float2* f2 = (float2*)g_tab4;
    long e = ti * GD + g;
    f2[2 * e] = make_float2(G, dv);                        // (x,y) of entry i
    if (i > 0) f2[2 * (e - GD) + 1] = make_float2(G, dv);  // (z,w) of entry i-1
}

// Hermite basis; returns row pointer into packed table for (tau, knot i).
__device__ __forceinline__ const float4* hermite4(float s, int tau,
    float& c00, float& c01, float& c10, float& c11,
    float& d00, float& d10, float& d11)
{
    float x = (s - S_MIN) * S_INVH;
    x = fminf(fmaxf(x, 0.f), (float)(NK - 1) - 1e-3f);
    int i = (int)x;
    float u = x - (float)i;
    float um = 1.f - u;
    c00 = (1.f + 2.f * u) * um * um;
    c01 = u * u * (3.f - 2.f * u);
    c10 = S_H * u * um * um;
    c11 = S_H * u * u * (u - 1.f);
    d00 = (6.f * u * u - 6.f * u) * S_INVH;
    d10 = fmaf(3.f * u, u, fmaf(-4.f, u, 1.f));
    d11 = fmaf(3.f * u, u, -2.f * u);
    return g_tab4 + (long)(tau * NK + i) * GD;
}

// ---------------- K1: one block per atom; lane=channel, item loop per wave ----------------
// xa[c][g] = (sum_j a[j][c] G[j][g])/200 accumulates in registers per lane (no
// cross-lane reduction needed: sum is over items). Table reads fully coalesced.
__global__ __launch_bounds__(256) void k1_emb(
    const float* __restrict__ Ri,
    float* __restrict__ dr_ws, float* __restrict__ xa_ws)
{
    __shared__ float4 a4s[JN];
    __shared__ float xar[4 * 400];   // per-wave partials [w][c*100+g]
    __shared__ float xas[400];

    int tid = threadIdx.x;
    int lane = tid & 63;
    int w = tid >> 6;
    int n = blockIdx.x;

    if (tid < JN) a4s[tid] = ((const float4*)Ri)[(long)n * JN + tid];
    __syncthreads();

    float x0 = 0.f, x1 = 0.f, x2 = 0.f, x3 = 0.f;   // channel = lane
    float y0 = 0.f, y1 = 0.f, y2 = 0.f, y3 = 0.f;   // channel = 64+lane (lane<36)

    for (int ii = 0; ii < 50; ++ii) {
        int j = w * 50 + ii;
        float4 a = a4s[j];           // same address across wave -> broadcast
        int tau = j / MAXNB;         // wave-uniform
        float c00, c01, c10, c11, d00, d10, d11;
        const float4* row = hermite4(a.x, tau, c00, c01, c10, c11, d00, d10, d11);
        {
            float4 r = row[lane];    // coalesced 1KB
            float G = r.x * c00 + r.z * c01 + r.y * c10 + r.w * c11;
            x0 = fmaf(a.x, G, x0); x1 = fmaf(a.y, G, x1);
            x2 = fmaf(a.z, G, x2); x3 = fmaf(a.w, G, x3);
        }
        if (lane < GD - 64) {
            float4 r = row[64 + lane];
            float G = r.x * c00 + r.z * c01 + r.y * c10 + r.w * c11;
            y0 = fmaf(a.x, G, y0); y1 = fmaf(a.y, G, y1);
            y2 = fmaf(a.z, G, y2); y3 = fmaf(a.w, G, y3);
        }
    }

    float* xw = xar + w * 400;
    xw[0 * GD + lane] = x0; xw[1 * GD + lane] = x1;
    xw[2 * GD + lane] = x2; xw[3 * GD + lane] = x3;
    if (lane < GD - 64) {
        xw[0 * GD + 64 + lane] = y0; xw[1 * GD + 64 + lane] = y1;
        xw[2 * GD + 64 + lane] = y2; xw[3 * GD + 64 + lane] = y3;
    }
    __syncthreads();

    for (int i = tid; i < 400; i += 256) {
        float v = (xar[i] + xar[400 + i] + xar[800 + i] + xar[1200 + i]) * INV200;
        xas[i] = v;
        xa_ws[(long)n * 400 + i] = v;
    }
    __syncthreads();

    for (int i = tid; i < DD; i += 256) {
        int gg = i / M2D, m = i % M2D;
        float v = 0.f;
#pragma unroll
        for (int c = 0; c < 4; ++c) v = fmaf(xas[c * GD + gg], xas[c * GD + m], v);
        dr_ws[(long)n * DD + i] = v;
    }
}

// ---------------- generic tiled fp32 GEMM: C = act(A@B + bias), per-type batch z ----------------
__global__ __launch_bounds__(256) void gemm_kernel(
    const float* __restrict__ Ab, const float* __restrict__ Bb,
    const float* __restrict__ biasb, float* __restrict__ Cb,
    int M, int Nn, int K, long sA, long sB, long sBias, long sC, int do_tanh)
{
    int t = blockIdx.z;
    const float* A = Ab + (long)t * sA;
    const float* B = Bb + (long)t * sB;
    const float* bias = biasb ? (biasb + (long)t * sBias) : nullptr;
    float* C = Cb + (long)t * sC;

    __shared__ float As[16 * 64];
    __shared__ float Bs[16 * 64];

    int tid = threadIdx.x;
    int n0 = blockIdx.x * 64;
    int m0 = blockIdx.y * 64;
    int tx = tid % 16, ty = tid / 16;

    float acc[4][4];
#pragma unroll
    for (int i = 0; i < 4; ++i)
#pragma unroll
        for (int j = 0; j < 4; ++j) acc[i][j] = 0.f;

    int a_m = tid / 4;
    int a_k = (tid % 4) * 4;
    int b_k = tid / 16;
    int b_n = (tid % 16) * 4;

    for (int k0 = 0; k0 < K; k0 += 16) {
        float4 av = *(const float4*)&A[(long)(m0 + a_m) * K + k0 + a_k];
        float4 bv = make_float4(0.f, 0.f, 0.f, 0.f);
        if (n0 + b_n < Nn) bv = *(const float4*)&B[(long)(k0 + b_k) * Nn + n0 + b_n];
        __syncthreads();
        As[(a_k + 0) * 64 + a_m] = av.x;
        As[(a_k + 1) * 64 + a_m] = av.y;
        As[(a_k + 2) * 64 + a_m] = av.z;
        As[(a_k + 3) * 64 + a_m] = av.w;
        *(float4*)&Bs[b_k * 64 + b_n] = bv;
        __syncthreads();
#pragma unroll
        for (int k = 0; k < 16; ++k) {
            float4 a4v = *(const float4*)&As[k * 64 + ty * 4];
            float4 b4v = *(const float4*)&Bs[k * 64 + tx * 4];
            acc[0][0] = fmaf(a4v.x, b4v.x, acc[0][0]);
            acc[0][1] = fmaf(a4v.x, b4v.y, acc[0][1]);
            acc[0][2] = fmaf(a4v.x, b4v.z, acc[0][2]);
            acc[0][3] = fmaf(a4v.x, b4v.w, acc[0][3]);
            acc[1][0] = fmaf(a4v.y, b4v.x, acc[1][0]);
            acc[1][1] = fmaf(a4v.y, b4v.y, acc[1][1]);
            acc[1][2] = fmaf(a4v.y, b4v.z, acc[1][2]);
            acc[1][3] = fmaf(a4v.y, b4v.w, acc[1][3]);
            acc[2][0] = fmaf(a4v.z, b4v.x, acc[2][0]);
            acc[2][1] = fmaf(a4v.z, b4v.y, acc[2][1]);
            acc[2][2] = fmaf(a4v.z, b4v.z, acc[2][2]);
            acc[2][3] = fmaf(a4v.z, b4v.w, acc[2][3]);
            acc[3][0] = fmaf(a4v.w, b4v.x, acc[3][0]);
            acc[3][1] = fmaf(a4v.w, b4v.y, acc[3][1]);
            acc[3][2] = fmaf(a4v.w, b4v.z, acc[3][2]);
            acc[3][3] = fmaf(a4v.w, b4v.w, acc[3][3]);
        }
    }
#pragma unroll
    for (int i = 0; i < 4; ++i) {
        int mm = m0 + ty * 4 + i;
#pragma unroll
        for (int j = 0; j < 4; ++j) {
            int nn = n0 + tx * 4 + j;
            if (nn < Nn) {
                float v = acc[i][j];
                if (bias) v += bias[nn];
                if (do_tanh) v = ftanh(v);
                C[(long)mm * Nn + nn] = v;
            }
        }
    }
}

// ---------------- K3a: per-atom Ei + Etot + dh0g (fw1T: coalesced reads) ----------------
__global__ __launch_bounds__(256) void k3a(
    const float* __restrict__ fh0, const float* __restrict__ fh1,
    const float* __restrict__ fw1T, const float* __restrict__ fw2, const float* __restrict__ fb2,
    float* __restrict__ out, float* __restrict__ dh0g)
{
    int n = blockIdx.x;
    int t = n / NA;
    int tid = threadIdx.x;
    __shared__ float u1s[FHD];
    __shared__ float red[256];

    float p = 0.f;
    if (tid < FHD) {
        float h1v = fh1[(long)n * FHD + tid];
        float w2v = fw2[t * FHD + tid];
        p = h1v * w2v;
        u1s[tid] = w2v * (1.f - h1v * h1v);
    }
    red[tid] = p;
    __syncthreads();
    for (int off = 128; off > 0; off >>= 1) {
        if (tid < off) red[tid] += red[tid + off];
        __syncthreads();
    }
    if (tid == 0) {
        float e = red[0] + fb2[t];
        out[OUT_EI + n] = e;
        atomicAdd(out, e);
    }
    if (tid < FHD) {
        const float* wT = fw1T + (long)t * FHD * FHD;
        float acc = 0.f;
        for (int o = 0; o < FHD; ++o) acc = fmaf(u1s[o], wT[o * FHD + tid], acc);
        float h0v = fh0[(long)n * FHD + tid];
        dh0g[(long)n * FHD + tid] = acc * (1.f - h0v * h0v);
    }
}

// ---------------- K3b: per-atom P, g-major float4 [n][g][c] (INV200 folded) ----------------
__global__ __launch_bounds__(256) void k3b(
    const float* __restrict__ Q, const float* __restrict__ xa, float* __restrict__ P4)
{
    int n = blockIdx.x;
    int tid = threadIdx.x;
    __shared__ float qs[DD];
    __shared__ float xs[400];
    for (int i = tid; i < DD; i += 256) qs[i] = Q[(long)n * DD + i];
    for (int i = tid; i < 400; i += 256) xs[i] = xa[(long)n * 400 + i];
    __syncthreads();
    for (int i = tid; i < 400; i += 256) {
        int c = i / GD, g = i % GD;
        float acc = 0.f;
        for (int m = 0; m < M2D; ++m) acc = fmaf(qs[g * M2D + m], xs[c * GD + m], acc);
        if (g < M2D) {
            for (int g2 = 0; g2 < GD; ++g2) acc = fmaf(qs[g2 * M2D + g], xs[c * GD + g2], acc);
        }
        P4[((long)n * GD + g) * 4 + c] = acc * INV200;
    }
}

// ---------------- K4: block=atom. Stage G/dG coalesced into LDS, compute thread-per-item ----------------
// Staging: lane <-> flat (item,channel) index, 25-channel chunks -> global loads
// touch <=3 contiguous row segments per instruction (no 64-line gather).
// Compute: thread j accumulates M1[c]=sum_g G*P[g][c], M2[c]=sum_g dG*P[g][c] in
// registers from LDS (stride-26 rows: 2-way bank aliasing = free; P broadcast).
// No cross-lane reduction anywhere (R6's 36K DS-cycles of shuffles eliminated).
#define KCH 25
#define KST 26
__global__ __launch_bounds__(256) void k4(
    const float* __restrict__ Ri, const float* __restrict__ dfeat,
    const float* __restrict__ ImageDR, const int* __restrict__ list_neigh,
    const float4* __restrict__ P4ws, float* __restrict__ out)
{
    __shared__ float4 a4s[JN];
    __shared__ float ss[JN];
    __shared__ float4 P4s[GD];
    __shared__ float Gst[JN * KST];
    __shared__ float Dst[JN * KST];
    __shared__ float facc3[3];
    __shared__ float vacc[6];

    int tid = threadIdx.x;
    int lane = tid & 63;
    int n = blockIdx.x;

    if (tid < JN) {
        float4 a = ((const float4*)Ri)[(long)n * JN + tid];
        a4s[tid] = a;
        ss[tid] = a.x;
    }
    if (tid < GD) P4s[tid] = P4ws[(long)n * GD + tid];
    if (tid < 3) facc3[tid] = 0.f;
    if (tid < 6) vacc[tid] = 0.f;
    __syncthreads();

    float M10 = 0.f, M11 = 0.f, M12 = 0.f, M13 = 0.f;
    float M20 = 0.f, M21 = 0.f, M22 = 0.f, M23 = 0.f;

    for (int cc = 0; cc < 4; ++cc) {
        int g0 = cc * KCH;
        // stage chunk: flat index over (item, channel)
#pragma unroll 2
        for (int f = tid; f < JN * KCH; f += 256) {
            int j = f / KCH;
            int ch = f - j * KCH;
            int tau = j / MAXNB;
            float c00, c01, c10, c11, d00, d10, d11;
            const float4* row = hermite4(ss[j], tau, c00, c01, c10, c11, d00, d10, d11);
            float4 r = row[g0 + ch];
            Gst[j * KST + ch] = r.x * c00 + r.z * c01 + r.y * c10 + r.w * c11;
            Dst[j * KST + ch] = (r.x - r.z) * d00 + r.y * d10 + r.w * d11;
        }
        __syncthreads();
        if (tid < JN) {
            const float* gr = Gst + tid * KST;
            const float* dr = Dst + tid * KST;
#pragma unroll
            for (int gl = 0; gl < KCH; ++gl) {
                float G = gr[gl];
                float Dv = dr[gl];
                float4 p = P4s[g0 + gl];   // same address across wave -> broadcast
                M10 = fmaf(p.x, G, M10); M11 = fmaf(p.y, G, M11);
                M12 = fmaf(p.z, G, M12); M13 = fmaf(p.w, G, M13);
                M20 = fmaf(p.x, Dv, M20); M21 = fmaf(p.y, Dv, M21);
                M22 = fmaf(p.z, Dv, M22); M23 = fmaf(p.w, Dv, M23);
            }
        }
        __syncthreads();
    }

    float v00 = 0.f, v01 = 0.f, v02 = 0.f, v11 = 0.f, v12 = 0.f, v22 = 0.f;
    if (tid < JN) {
        long item = (long)n * JN + tid;
        float4 a = a4s[tid];
        float ds = a.x * M20 + a.y * M21 + a.z * M22 + a.w * M23;
        float dEda0 = M10 + ds, dEda1 = M11, dEda2 = M12, dEda3 = M13;

        const float4* dfp = (const float4*)(dfeat + item * 12);
        float4 q0 = dfp[0], q1 = dfp[1], q2 = dfp[2];
        float dEdx0 = dEda0 * q0.x + dEda1 * q0.w + dEda2 * q1.z + dEda3 * q2.y;
        float dEdx1 = dEda0 * q0.y + dEda1 * q1.x + dEda2 * q1.w + dEda3 * q2.z;
        float dEdx2 = dEda0 * q0.z + dEda1 * q1.y + dEda2 * q2.x + dEda3 * q2.w;

        atomicAdd(&facc3[0], dEdx0);
        atomicAdd(&facc3[1], dEdx1);
        atomicAdd(&facc3[2], dEdx2);

        int ln = list_neigh[item];
        if (ln > 0) {
            int ii2 = ln - 1;
            if (ii2 > NATOMS - 1) ii2 = NATOMS - 1;
            atomicAdd(&out[OUT_F + ii2 * 3 + 0], dEdx0);
            atomicAdd(&out[OUT_F + ii2 * 3 + 1], dEdx1);
            atomicAdd(&out[OUT_F + ii2 * 3 + 2], dEdx2);
            const float* im = ImageDR + item * 3;
            v00 = im[0] * dEdx0; v01 = im[0] * dEdx1; v02 = im[0] * dEdx2;
            v11 = im[1] * dEdx1; v12 = im[1] * dEdx2; v22 = im[2] * dEdx2;
        }
    }

#pragma unroll
    for (int mask = 32; mask > 0; mask >>= 1) {
        v00 += __shfl_xor(v00, mask);
        v01 += __shfl_xor(v01, mask);
        v02 += __shfl_xor(v02, mask);
        v11 += __shfl_xor(v11, mask);
        v12 += __shfl_xor(v12, mask);
        v22 += __shfl_xor(v22, mask);
    }
    if (lane == 0) {
        atomicAdd(&vacc[0], v00);
        atomicAdd(&vacc[1], v01);
        atomicAdd(&vacc[2], v02);
        atomicAdd(&vacc[3], v11);
        atomicAdd(&vacc[4], v12);
        atomicAdd(&vacc[5], v22);
    }
    __syncthreads();
    if (tid < 3) atomicAdd(&out[OUT_F + n * 3 + tid], -facc3[tid]);
    if (tid < 9) {
        const int vmap[9] = {0, 1, 2, 1, 3, 4, 2, 4, 5};
        atomicAdd(&out[OUT_V + tid], vacc[vmap[tid]]);
    }
}

extern "C" void kernel_launch(void* const* d_in, const int* in_sizes, int n_in,
                              void* d_out, int out_size, void* d_ws, size_t ws_size,
                              hipStream_t stream) {
    const float* Ri = (const float*)d_in[0];
    const float* dfeat = (const float*)d_in[1];
    const float* ImageDR = (const float*)d_in[2];
    const float* tv = (const float*)d_in[3];
    const float* ew0 = (const float*)d_in[4];
    const float* eb0 = (const float*)d_in[5];
    const float* ew1 = (const float*)d_in[6];
    const float* eb1 = (const float*)d_in[7];
    const float* ew2 = (const float*)d_in[8];
    const float* eb2 = (const float*)d_in[9];
    const float* fw0 = (const float*)d_in[10];
    const float* fb0 = (const float*)d_in[11];
    const float* fw1 = (const float*)d_in[12];
    const float* fb1 = (const float*)d_in[13];
    const float* fw2 = (const float*)d_in[14];
    const float* fb2 = (const float*)d_in[15];
    const int* list_neigh = (const int*)d_in[16];

    float* out = (float*)d_out;
    float* ws = (float*)d_ws;
    float* drQ = ws + WS_DRQ;
    float* xa = ws + WS_XA;
    float* P = ws + WS_P;
    float* fh0 = ws + WS_FH0;
    float* fh1 = ws + WS_FH1;
    float* dh0g = ws + WS_DH0G;
    float* fw0T = ws + WS_FW0T;
    float* fw1T = ws + WS_FW1T;   // aliases P; consumed by k3a before k3b writes P

    hipMemsetAsync(d_out, 0, (size_t)out_size * sizeof(float), stream);

    k_setup<<<(NTYPES * DD * FHD + 255) / 256, 256, 0, stream>>>(fw0, fw0T, fw1, fw1T);
    k_table_h<<<(NTYPES * NK + 255) / 256, 256, 0, stream>>>(ew0, eb0, ew1, eb1, tv);
    k_table_g<<<(NTYPES * NK * GD + 255) / 256, 256, 0, stream>>>(ew2, eb2);

    k1_emb<<<NATOMS, 256, 0, stream>>>(Ri, drQ, xa);

    // fit forward: fh0 = tanh(dr @ fw0 + fb0), fh1 = tanh(fh0 @ fw1 + fb1)
    gemm_kernel<<<dim3(4, 32, 2), 256, 0, stream>>>(drQ, fw0, fb0, fh0,
        2048, 240, 1600, 2048L * 1600, 1600L * 240, 240L, 2048L * 240, 1);
    gemm_kernel<<<dim3(4, 32, 2), 256, 0, stream>>>(fh0, fw1, fb1, fh1,
        2048, 240, 240, 2048L * 240, 240L * 240, 240L, 2048L * 240, 1);

    k3a<<<NATOMS, 256, 0, stream>>>(fh0, fh1, fw1T, fw2, fb2, out, dh0g);

    // Q = dh0g @ fw0^T  (overwrites dr buffer)
    gemm_kernel<<<dim3(25, 32, 2), 256, 0, stream>>>(dh0g, fw0T, nullptr, drQ,
        2048, 1600, 240, 2048L * 240, 240L * 1600, 0L, 2048L * 1600, 0);

    k3b<<<NATOMS, 256, 0, stream>>>(drQ, xa, P);

    k4<<<NATOMS, 256, 0, stream>>>(Ri, dfeat, ImageDR, list_neigh,
        (const float4*)P, out);
}

// Round 8
// 599.685 us; speedup vs baseline: 1.4745x; 1.1828x over previous
//
#include <hip/hip_runtime.h>

// Problem constants
#define NATOMS 4096
#define NTYPES 2
#define NA 2048
#define MAXNB 100
#define JN 200          // neighbors per atom
#define TFD 4
#define E0 25
#define E1 50
#define GD 100
#define M2D 16
#define DD 1600
#define FHD 240
#define INV200 (1.0f/200.0f)

// Output layout (floats): Etot@0 (1), Ei@1 (4096), F@4097 (12288), Virial@16385 (9)
#define OUT_EI 1
#define OUT_F 4097
#define OUT_V 16385

// Workspace layout (floats). Total ~17.0M floats = 68 MB.
#define WS_Q 0L                  // Q fp32 [2][2048][1600] = 6,553,600 (written by gemmQ)
#define WS_FW1T 0L               // fp32 fw1T [2][240][240] aliases Q head; consumed by k3a BEFORE gemmQ
#define WS_DRB 6553600L          // dr bf16 [2][2048][1600] = 3,276,800 float-slots
#define WS_XA 9830400L           // 4096*400
#define WS_P 11468800L           // 4096*400 (g-major float4 [n][g][c])
#define WS_FH0 13107200L         // fp32 [4096][240]
#define WS_FH1 14090240L         // fp32 [4096][240]
#define WS_DH0GB 15073280L       // bf16 [2][2048][256] zero-padded K
#define WS_FH0B 15597568L        // bf16 [2][2048][256] zero-padded K
#define WS_FW0TB 16121856L       // bf16 [2][256][1600] (rows>=240 garbage-ok)
#define WS_FW0B 16531456L        // bf16 [2][1600][256] (cols>=240 zero)
#define WS_FW1TB 16941056L       // bf16 [2][256][256] (cols>=240 zero, rows>=240 garbage-ok)

// G(s) lookup table: 1-D function of s per type (temb const per type).
#define NK 1024
#define S_MIN (-8.0f)
#define S_H 0.015625f
#define S_INVH 64.0f
__device__ float4 g_tab4[NTYPES * NK * GD];
__device__ float2 g_th1[NTYPES * NK * E1];

typedef __attribute__((ext_vector_type(8))) short bf16x8;
typedef __attribute__((ext_vector_type(4))) float f32x4;

__device__ __forceinline__ float ftanh(float x) {
    float ax = fabsf(x);
    float e = __expf(-2.0f * ax);
    float t = (1.0f - e) / (1.0f + e);
    return copysignf(t, x);
}

__device__ __forceinline__ unsigned short f2b(float f) {
    union { float f; unsigned u; } v; v.f = f;
    unsigned r = (v.u + 0x7FFF + ((v.u >> 16) & 1)) >> 16;
    return (unsigned short)r;
}

// ---------------- setup: bf16 weight transposes + fp32 fw1T ----------------
__global__ void k_setup(const float* __restrict__ fw0, const float* __restrict__ fw1,
                        unsigned short* __restrict__ fw0Tb, unsigned short* __restrict__ fw0b,
                        float* __restrict__ fw1T, unsigned short* __restrict__ fw1Tb) {
    int idx = blockIdx.x * 256 + threadIdx.x;
    if (idx < NTYPES * FHD * DD) {           // fw0Tb [t][o][d] <- fw0[t][d][o]
        int t = idx / (FHD * DD);
        int r = idx % (FHD * DD);
        int o = r / DD, d = r % DD;
        fw0Tb[(long)t * 256 * DD + (long)o * DD + d] =
            f2b(fw0[(long)t * DD * FHD + (long)d * FHD + o]);
    }
    if (idx < NTYPES * DD * 256) {           // fw0b [t][d][kk] (kk>=240 -> 0)
        int t = idx / (DD * 256);
        int r = idx % (DD * 256);
        int d = r / 256, kk = r % 256;
        float v = (kk < FHD) ? fw0[(long)t * DD * FHD + (long)d * FHD + kk] : 0.f;
        fw0b[idx] = f2b(v);
    }
    if (idx < NTYPES * FHD * FHD) {          // fw1T fp32 [t][o][i]
        int t = idx / (FHD * FHD);
        int r = idx % (FHD * FHD);
        int o = r / FHD, i = r % FHD;
        fw1T[idx] = fw1[(long)t * FHD * FHD + (long)i * FHD + o];
    }
    if (idx < NTYPES * FHD * 256) {          // fw1Tb [t][o][kk]
        int t = idx / (FHD * 256);
        int r = idx % (FHD * 256);
        int o = r / 256, kk = r % 256;
        float v = (kk < FHD) ? fw1[(long)t * FHD * FHD + (long)kk * FHD + o] : 0.f;
        fw1Tb[(long)t * 256 * 256 + (long)o * 256 + kk] = f2b(v);
    }
}

// ---------------- table stage 1 ----------------
__global__ __launch_bounds__(256) void k_table_h(
    const float* __restrict__ ew0, const float* __restrict__ eb0,
    const float* __restrict__ ew1, const float* __restrict__ eb1,
    const float* __restrict__ tv)
{
    int idx = blockIdx.x * 256 + threadIdx.x;
    if (idx >= NTYPES * NK) return;
    int t = idx / NK, i = idx % NK;
    float s = S_MIN + (float)i * S_H;

    float h0[E0], t0[E0];
#pragma unroll
    for (int k = 0; k < E0; ++k) {
        float c = eb0[k];
#pragma unroll
        for (int f = 0; f < TFD; ++f) c = fmaf(tv[t * TFD + f], ew0[(1 + f) * E0 + k], c);
        float h = ftanh(fmaf(s, ew0[k], c));
        h0[k] = h;
        t0[k] = (1.f - h * h) * ew0[k];
    }
#pragma unroll 2
    for (int l = 0; l < E1; ++l) {
        float acc = eb1[l], dacc = 0.f;
#pragma unroll
        for (int k = 0; k < E0; ++k) {
            float w = ew1[k * E1 + l];
            acc = fmaf(h0[k], w, acc);
            dacc = fmaf(t0[k], w, dacc);
        }
        float h = ftanh(acc);
        g_th1[(long)idx * E1 + l] = make_float2(h, (1.f - h * h) * dacc);
    }
}

// ---------------- table stage 2 ----------------
__global__ __launch_bounds__(256) void k_table_g(
    const float* __restrict__ ew2, const float* __restrict__ eb2)
{
    long idx = (long)blockIdx.x * 256 + threadIdx.x;
    if (idx >= (long)NTYPES * NK * GD) return;
    int g = idx % GD;
    long ti = idx / GD;
    int i = ti % NK;

    const float2* hv = g_th1 + ti * E1;
    float acc = eb2[g], dacc = 0.f;
#pragma unroll 5
    for (int l = 0; l < E1; ++l) {
        float2 x = hv[l];
        float w = ew2[l * GD + g];
        acc = fmaf(x.x, w, acc);
        dacc = fmaf(x.y, w, dacc);
    }
    float G = ftanh(acc);
    float dv = (1.f - G * G) * dacc;

    float2* f2 = (float2*)g_tab4;
    long e = ti * GD + g;
    f2[2 * e] = make_float2(G, dv);
    if (i > 0) f2[2 * (e - GD) + 1] = make_float2(G, dv);
}

__device__ __forceinline__ const float4* hermite4(float s, int tau,
    float& c00, float& c01, float& c10, float& c11,
    float& d00, float& d10, float& d11)
{
    float x = (s - S_MIN) * S_INVH;
    x = fminf(fmaxf(x, 0.f), (float)(NK - 1) - 1e-3f);
    int i = (int)x;
    float u = x - (float)i;
    float um = 1.f - u;
    c00 = (1.f + 2.f * u) * um * um;
    c01 = u * u * (3.f - 2.f * u);
    c10 = S_H * u * um * um;
    c11 = S_H * u * u * (u - 1.f);
    d00 = (6.f * u * u - 6.f * u) * S_INVH;
    d10 = fmaf(3.f * u, u, fmaf(-4.f, u, 1.f));
    d11 = fmaf(3.f * u, u, -2.f * u);
    return g_tab4 + (long)(tau * NK + i) * GD;
}

// ---------------- K1: lane=channel, item loop per wave; writes dr as bf16 ----------------
__global__ __launch_bounds__(256) void k1_emb(
    const float* __restrict__ Ri,
    unsigned short* __restrict__ drb, float* __restrict__ xa_ws)
{
    __shared__ float4 a4s[JN];
    __shared__ float xar[4 * 400];
    __shared__ float xas[400];

    int tid = threadIdx.x;
    int lane = tid & 63;
    int w = tid >> 6;
    int n = blockIdx.x;

    if (tid < JN) a4s[tid] = ((const float4*)Ri)[(long)n * JN + tid];
    __syncthreads();

    float x0 = 0.f, x1 = 0.f, x2 = 0.f, x3 = 0.f;
    float y0 = 0.f, y1 = 0.f, y2 = 0.f, y3 = 0.f;

    for (int ii = 0; ii < 50; ++ii) {
        int j = w * 50 + ii;
        float4 a = a4s[j];
        int tau = j / MAXNB;
        float c00, c01, c10, c11, d00, d10, d11;
        const float4* row = hermite4(a.x, tau, c00, c01, c10, c11, d00, d10, d11);
        {
            float4 r = row[lane];
            float G = r.x * c00 + r.z * c01 + r.y * c10 + r.w * c11;
            x0 = fmaf(a.x, G, x0); x1 = fmaf(a.y, G, x1);
            x2 = fmaf(a.z, G, x2); x3 = fmaf(a.w, G, x3);
        }
        if (lane < GD - 64) {
            float4 r = row[64 + lane];
            float G = r.x * c00 + r.z * c01 + r.y * c10 + r.w * c11;
            y0 = fmaf(a.x, G, y0); y1 = fmaf(a.y, G, y1);
            y2 = fmaf(a.z, G, y2); y3 = fmaf(a.w, G, y3);
        }
    }

    float* xw = xar + w * 400;
    xw[0 * GD + lane] = x0; xw[1 * GD + lane] = x1;
    xw[2 * GD + lane] = x2; xw[3 * GD + lane] = x3;
    if (lane < GD - 64) {
        xw[0 * GD + 64 + lane] = y0; xw[1 * GD + 64 + lane] = y1;
        xw[2 * GD + 64 + lane] = y2; xw[3 * GD + 64 + lane] = y3;
    }
    __syncthreads();

    for (int i = tid; i < 400; i += 256) {
        float v = (xar[i] + xar[400 + i] + xar[800 + i] + xar[1200 + i]) * INV200;
        xas[i] = v;
        xa_ws[(long)n * 400 + i] = v;
    }
    __syncthreads();

    for (int i = tid; i < DD; i += 256) {
        int gg = i / M2D, m = i % M2D;
        float v = 0.f;
#pragma unroll
        for (int c = 0; c < 4; ++c) v = fmaf(xas[c * GD + gg], xas[c * GD + m], v);
        drb[(long)n * DD + i] = f2b(v);
    }
}

// ---------------- MFMA bf16 GEMM: C = act(A @ BT^T + bias) ----------------
// A [M x K] bf16 row-major; BT [Npad x K] bf16 row-major (B pre-transposed so
// both fragment reads are contiguous-in-K ds_read_b128). K, M multiples of 64.
// 64x64 block tile, 4 waves in 2x2, each wave 2x2 of 16x16x32 mfma tiles.
// Optional bf16 side-output Cb16 [M x Npad] (zero-filled beyond N) for chaining.
__global__ __launch_bounds__(256) void mgemm(
    const unsigned short* __restrict__ Ab, const unsigned short* __restrict__ BTb,
    const float* __restrict__ biasb, float* __restrict__ Cb, unsigned short* __restrict__ Cbf,
    int M, int N, int K, int Npad,
    long sA, long sBT, long sBias, long sC, long sCbf, int do_tanh)
{
    int t = blockIdx.z;
    const unsigned short* A = Ab + (long)t * sA;
    const unsigned short* BT = BTb + (long)t * sBT;
    const float* bias = biasb ? biasb + (long)t * sBias : nullptr;
    float* C = Cb + (long)t * sC;
    unsigned short* Cb16 = Cbf ? Cbf + (long)t * sCbf : nullptr;

    __shared__ __align__(16) unsigned short As[64 * 72];
    __shared__ __align__(16) unsigned short Bs[64 * 72];

    int tid = threadIdx.x;
    int m0 = blockIdx.x * 64;
    int n0 = blockIdx.y * 64;

    int lane = tid & 63;
    int w = tid >> 6;
    int wm = (w & 1) * 32;
    int wn = (w >> 1) * 32;
    int fm = lane & 15;
    int q = lane >> 4;

    f32x4 acc[2][2] = {};

    int sr = tid >> 2;
    int sc = tid & 3;

    const unsigned short* Ar = A + (long)(m0 + sr) * K + sc * 8;
    const unsigned short* Br = BT + (long)(n0 + sr) * K + sc * 8;
    unsigned short* Asw = As + sr * 72 + sc * 8;
    unsigned short* Bsw = Bs + sr * 72 + sc * 8;

    for (int k0 = 0; k0 < K; k0 += 64) {
        uint4 av0 = *(const uint4*)(Ar + k0);
        uint4 av1 = *(const uint4*)(Ar + k0 + 32);
        uint4 bv0 = *(const uint4*)(Br + k0);
        uint4 bv1 = *(const uint4*)(Br + k0 + 32);
        __syncthreads();
        *(uint4*)(Asw) = av0;
        *(uint4*)(Asw + 32) = av1;
        *(uint4*)(Bsw) = bv0;
        *(uint4*)(Bsw + 32) = bv1;
        __syncthreads();
#pragma unroll
        for (int kk = 0; kk < 64; kk += 32) {
            bf16x8 af0 = *(const bf16x8*)(As + (wm + fm) * 72 + kk + q * 8);
            bf16x8 af1 = *(const bf16x8*)(As + (wm + 16 + fm) * 72 + kk + q * 8);
            bf16x8 bg0 = *(const bf16x8*)(Bs + (wn + fm) * 72 + kk + q * 8);
            bf16x8 bg1 = *(const bf16x8*)(Bs + (wn + 16 + fm) * 72 + kk + q * 8);
            acc[0][0] = __builtin_amdgcn_mfma_f32_16x16x32_bf16(af0, bg0, acc[0][0], 0, 0, 0);
            acc[0][1] = __builtin_amdgcn_mfma_f32_16x16x32_bf16(af0, bg1, acc[0][1], 0, 0, 0);
            acc[1][0] = __builtin_amdgcn_mfma_f32_16x16x32_bf16(af1, bg0, acc[1][0], 0, 0, 0);
            acc[1][1] = __builtin_amdgcn_mfma_f32_16x16x32_bf16(af1, bg1, acc[1][1], 0, 0, 0);
        }
    }

    // C/D layout: col = lane&15, row = q*4 + reg
#pragma unroll
    for (int i = 0; i < 2; ++i) {
#pragma unroll
        for (int j = 0; j < 2; ++j) {
            int col = n0 + wn + j * 16 + fm;
            int rb = m0 + wm + i * 16 + q * 4;
            bool ok = col < N;
            float bv = (bias && ok) ? bias[col] : 0.f;
#pragma unroll
            for (int r = 0; r < 4; ++r) {
                float v = acc[i][j][r] + bv;
                if (do_tanh) v = ftanh(v);
                if (ok) C[(long)(rb + r) * N + col] = v;
                if (Cb16) Cb16[(long)(rb + r) * Npad + col] = ok ? f2b(v) : (unsigned short)0;
            }
        }
    }
}

// ---------------- K3a: per-atom Ei + Etot + dh0g (bf16, K zero-padded) ----------------
__global__ __launch_bounds__(256) void k3a(
    const float* __restrict__ fh0, const float* __restrict__ fh1,
    const float* __restrict__ fw1T, const float* __restrict__ fw2, const float* __restrict__ fb2,
    float* __restrict__ out, unsigned short* __restrict__ dh0gb)
{
    int n = blockIdx.x;
    int t = n / NA;
    int tid = threadIdx.x;
    __shared__ float u1s[FHD];
    __shared__ float red[256];

    float p = 0.f;
    if (tid < FHD) {
        float h1v = fh1[(long)n * FHD + tid];
        float w2v = fw2[t * FHD + tid];
        p = h1v * w2v;
        u1s[tid] = w2v * (1.f - h1v * h1v);
    }
    red[tid] = p;
    __syncthreads();
    for (int off = 128; off > 0; off >>= 1) {
        if (tid < off) red[tid] += red[tid + off];
        __syncthreads();
    }
    if (tid == 0) {
        float e = red[0] + fb2[t];
        out[OUT_EI + n] = e;
        atomicAdd(out, e);
    }
    float val = 0.f;
    if (tid < FHD) {
        const float* wT = fw1T + (long)t * FHD * FHD;
        float acc = 0.f;
        for (int o = 0; o < FHD; ++o) acc = fmaf(u1s[o], wT[o * FHD + tid], acc);
        float h0v = fh0[(long)n * FHD + tid];
        val = acc * (1.f - h0v * h0v);
    }
    dh0gb[(long)n * 256 + tid] = (tid < FHD) ? f2b(val) : (unsigned short)0;
}

// ---------------- K3b: per-atom P, g-major float4 [n][g][c] ----------------
__global__ __launch_bounds__(256) void k3b(
    const float* __restrict__ Q, const float* __restrict__ xa, float* __restrict__ P4)
{
    int n = blockIdx.x;
    int tid = threadIdx.x;
    __shared__ float qs[DD];
    __shared__ float xs[400];
    for (int i = tid; i < DD; i += 256) qs[i] = Q[(long)n * DD + i];
    for (int i = tid; i < 400; i += 256) xs[i] = xa[(long)n * 400 + i];
    __syncthreads();
    for (int i = tid; i < 400; i += 256) {
        int c = i / GD, g = i % GD;
        float acc = 0.f;
        for (int m = 0; m < M2D; ++m) acc = fmaf(qs[g * M2D + m], xs[c * GD + m], acc);
        if (g < M2D) {
            for (int g2 = 0; g2 < GD; ++g2) acc = fmaf(qs[g2 * M2D + g], xs[c * GD + g2], acc);
        }
        P4[((long)n * GD + g) * 4 + c] = acc * INV200;
    }
}

// ---------------- K4: block=atom; coalesced G/dG staging; thread-per-item compute ----------------
#define KCH 25
#define KST 27
__global__ __launch_bounds__(256) void k4(
    const float* __restrict__ Ri, const float* __restrict__ dfeat,
    const float* __restrict__ ImageDR, const int* __restrict__ list_neigh,
    const float4* __restrict__ P4ws, float* __restrict__ out)
{
    __shared__ float4 a4s[JN];
    __shared__ float ss[JN];
    __shared__ float4 P4s[GD];
    __shared__ float Gst[JN * KST];
    __shared__ float Dst[JN * KST];
    __shared__ float facc3[3];
    __shared__ float vacc[6];

    int tid = threadIdx.x;
    int lane = tid & 63;
    int n = blockIdx.x;

    if (tid < JN) {
        float4 a = ((const float4*)Ri)[(long)n * JN + tid];
        a4s[tid] = a;
        ss[tid] = a.x;
    }
    if (tid < GD) P4s[tid] = P4ws[(long)n * GD + tid];
    if (tid < 3) facc3[tid] = 0.f;
    if (tid < 6) vacc[tid] = 0.f;
    __syncthreads();

    float M10 = 0.f, M11 = 0.f, M12 = 0.f, M13 = 0.f;
    float M20 = 0.f, M21 = 0.f, M22 = 0.f, M23 = 0.f;

    for (int cc = 0; cc < 4; ++cc) {
        int g0 = cc * KCH;
#pragma unroll 2
        for (int f = tid; f < JN * KCH; f += 256) {
            int j = f / KCH;
            int ch = f - j * KCH;
            int tau = j / MAXNB;
            float c00, c01, c10, c11, d00, d10, d11;
            const float4* row = hermite4(ss[j], tau, c00, c01, c10, c11, d00, d10, d11);
            float4 r = row[g0 + ch];
            Gst[j * KST + ch] = r.x * c00 + r.z * c01 + r.y * c10 + r.w * c11;
            Dst[j * KST + ch] = (r.x - r.z) * d00 + r.y * d10 + r.w * d11;
        }
        __syncthreads();
        if (tid < JN) {
            const float* gr = Gst + tid * KST;
            const float* dr = Dst + tid * KST;
#pragma unroll
            for (int gl = 0; gl < KCH; ++gl) {
                float G = gr[gl];
                float Dv = dr[gl];
                float4 p = P4s[g0 + gl];
                M10 = fmaf(p.x, G, M10); M11 = fmaf(p.y, G, M11);
                M12 = fmaf(p.z, G, M12); M13 = fmaf(p.w, G, M13);
                M20 = fmaf(p.x, Dv, M20); M21 = fmaf(p.y, Dv, M21);
                M22 = fmaf(p.z, Dv, M22); M23 = fmaf(p.w, Dv, M23);
            }
        }
        __syncthreads();
    }

    float v00 = 0.f, v01 = 0.f, v02 = 0.f, v11 = 0.f, v12 = 0.f, v22 = 0.f;
    if (tid < JN) {
        long item = (long)n * JN + tid;
        float4 a = a4s[tid];
        float ds = a.x * M20 + a.y * M21 + a.z * M22 + a.w * M23;
        float dEda0 = M10 + ds, dEda1 = M11, dEda2 = M12, dEda3 = M13;

        const float4* dfp = (const float4*)(dfeat + item * 12);
        float4 q0 = dfp[0], q1 = dfp[1], q2 = dfp[2];
        float dEdx0 = dEda0 * q0.x + dEda1 * q0.w + dEda2 * q1.z + dEda3 * q2.y;
        float dEdx1 = dEda0 * q0.y + dEda1 * q1.x + dEda2 * q1.w + dEda3 * q2.z;
        float dEdx2 = dEda0 * q0.z + dEda1 * q1.y + dEda2 * q2.x + dEda3 * q2.w;

        atomicAdd(&facc3[0], dEdx0);
        atomicAdd(&facc3[1], dEdx1);
        atomicAdd(&facc3[2], dEdx2);

        int ln = list_neigh[item];
        if (ln > 0) {
            int ii2 = ln - 1;
            if (ii2 > NATOMS - 1) ii2 = NATOMS - 1;
            atomicAdd(&out[OUT_F + ii2 * 3 + 0], dEdx0);
            atomicAdd(&out[OUT_F + ii2 * 3 + 1], dEdx1);
            atomicAdd(&out[OUT_F + ii2 * 3 + 2], dEdx2);
            const float* im = ImageDR + item * 3;
            v00 = im[0] * dEdx0; v01 = im[0] * dEdx1; v02 = im[0] * dEdx2;
            v11 = im[1] * dEdx1; v12 = im[1] * dEdx2; v22 = im[2] * dEdx2;
        }
    }

#pragma unroll
    for (int mask = 32; mask > 0; mask >>= 1) {
        v00 += __shfl_xor(v00, mask);
        v01 += __shfl_xor(v01, mask);
        v02 += __shfl_xor(v02, mask);
        v11 += __shfl_xor(v11, mask);
        v12 += __shfl_xor(v12, mask);
        v22 += __shfl_xor(v22, mask);
    }
    if (lane == 0) {
        atomicAdd(&vacc[0], v00);
        atomicAdd(&vacc[1], v01);
        atomicAdd(&vacc[2], v02);
        atomicAdd(&vacc[3], v11);
        atomicAdd(&vacc[4], v12);
        atomicAdd(&vacc[5], v22);
    }
    __syncthreads();
    if (tid < 3) atomicAdd(&out[OUT_F + n * 3 + tid], -facc3[tid]);
    if (tid < 9) {
        const int vmap[9] = {0, 1, 2, 1, 3, 4, 2, 4, 5};
        atomicAdd(&out[OUT_V + tid], vacc[vmap[tid]]);
    }
}

extern "C" void kernel_launch(void* const* d_in, const int* in_sizes, int n_in,
                              void* d_out, int out_size, void* d_ws, size_t ws_size,
                              hipStream_t stream) {
    const float* Ri = (const float*)d_in[0];
    const float* dfeat = (const float*)d_in[1];
    const float* ImageDR = (const float*)d_in[2];
    const float* tv = (const float*)d_in[3];
    const float* ew0 = (const float*)d_in[4];
    const float* eb0 = (const float*)d_in[5];
    const float* ew1 = (const float*)d_in[6];
    const float* eb1 = (const float*)d_in[7];
    const float* ew2 = (const float*)d_in[8];
    const float* eb2 = (const float*)d_in[9];
    const float* fw0 = (const float*)d_in[10];
    const float* fb0 = (const float*)d_in[11];
    const float* fw1 = (const float*)d_in[12];
    const float* fb1 = (const float*)d_in[13];
    const float* fw2 = (const float*)d_in[14];
    const float* fb2 = (const float*)d_in[15];
    const int* list_neigh = (const int*)d_in[16];

    float* out = (float*)d_out;
    float* ws = (float*)d_ws;
    float* Q = ws + WS_Q;
    float* fw1T = ws + WS_FW1T;
    unsigned short* drb = (unsigned short*)(ws + WS_DRB);
    float* xa = ws + WS_XA;
    float* P = ws + WS_P;
    float* fh0 = ws + WS_FH0;
    float* fh1 = ws + WS_FH1;
    unsigned short* dh0gb = (unsigned short*)(ws + WS_DH0GB);
    unsigned short* fh0b = (unsigned short*)(ws + WS_FH0B);
    unsigned short* fw0Tb = (unsigned short*)(ws + WS_FW0TB);
    unsigned short* fw0b = (unsigned short*)(ws + WS_FW0B);
    unsigned short* fw1Tb = (unsigned short*)(ws + WS_FW1TB);

    hipMemsetAsync(d_out, 0, (size_t)out_size * sizeof(float), stream);

    k_setup<<<(NTYPES * DD * 256 + 255) / 256, 256, 0, stream>>>(
        fw0, fw1, fw0Tb, fw0b, fw1T, fw1Tb);
    k_table_h<<<(NTYPES * NK + 255) / 256, 256, 0, stream>>>(ew0, eb0, ew1, eb1, tv);
    k_table_g<<<(NTYPES * NK * GD + 255) / 256, 256, 0, stream>>>(ew2, eb2);

    k1_emb<<<NATOMS, 256, 0, stream>>>(Ri, drb, xa);

    // fh0 = tanh(dr @ fw0 + fb0)  [+ bf16 copy for next GEMM]
    mgemm<<<dim3(32, 4, 2), 256, 0, stream>>>(
        drb, fw0Tb, fb0, fh0, fh0b,
        2048, 240, 1600, 256,
        2048L * 1600, 256L * 1600, 240L, 2048L * 240, 2048L * 256, 1);
    // fh1 = tanh(fh0 @ fw1 + fb1)
    mgemm<<<dim3(32, 4, 2), 256, 0, stream>>>(
        fh0b, fw1Tb, fb1, fh1, nullptr,
        2048, 240, 256, 0,
        2048L * 256, 256L * 256, 240L, 2048L * 240, 0L, 1);

    k3a<<<NATOMS, 256, 0, stream>>>(fh0, fh1, fw1T, fw2, fb2, out, dh0gb);

    // Q = dh0g @ fw0^T  (overwrites fw1T alias region; k3a already consumed it)
    mgemm<<<dim3(32, 25, 2), 256, 0, stream>>>(
        dh0gb, fw0b, nullptr, Q, nullptr,
        2048, 1600, 256, 0,
        2048L * 256, 1600L * 256, 0L, 2048L * 1600, 0L, 0);

    k3b<<<NATOMS, 256, 0, stream>>>(Q, xa, P);

    k4<<<NATOMS, 256, 0, stream>>>(Ri, dfeat, ImageDR, list_neigh,
        (const float4*)P, out);
}

// Round 9
// 570.285 us; speedup vs baseline: 1.5506x; 1.0516x over previous
//
#include <hip/hip_runtime.h>

// Problem constants
#define NATOMS 4096
#define NTYPES 2
#define NA 2048
#define MAXNB 100
#define JN 200          // neighbors per atom
#define TFD 4
#define E0 25
#define E1 50
#define GD 100
#define M2D 16
#define DD 1600
#define FHD 240
#define INV200 (1.0f/200.0f)

// Output layout (floats): Etot@0 (1), Ei@1 (4096), F@4097 (12288), Virial@16385 (9)
#define OUT_EI 1
#define OUT_F 4097
#define OUT_V 16385

// Workspace layout (floats). Total ~17.0M floats = 68 MB.
#define WS_Q 0L                  // Q fp32 [2][2048][1600] = 6,553,600 (written by gemmQ)
#define WS_FW1T 0L               // fp32 fw1T [2][240][240] aliases Q head; consumed by k3a BEFORE gemmQ
#define WS_DRB 6553600L          // dr bf16 [2][2048][1600] = 3,276,800 float-slots
#define WS_XA 9830400L           // 4096*400
#define WS_P 11468800L           // 4096*400 (g-major float4 [n][g][c])
#define WS_FH0 13107200L         // fp32 [4096][240]
#define WS_FH1 14090240L         // fp32 [4096][240]
#define WS_DH0GB 15073280L       // bf16 [2][2048][256] zero-padded K
#define WS_FH0B 15597568L        // bf16 [2][2048][256] zero-padded K
#define WS_FW0TB 16121856L       // bf16 [2][256][1600] (rows>=240 garbage-ok)
#define WS_FW0B 16531456L        // bf16 [2][1600][256] (cols>=240 zero)
#define WS_FW1TB 16941056L       // bf16 [2][256][256] (cols>=240 zero, rows>=240 garbage-ok)

// G(s) lookup table: 1-D function of s per type (temb const per type).
#define NK 1024
#define S_MIN (-8.0f)
#define S_H 0.015625f
#define S_INVH 64.0f
__device__ float4 g_tab4[NTYPES * NK * GD];
__device__ float2 g_th1[NTYPES * NK * E1];

typedef __attribute__((ext_vector_type(8))) short bf16x8;
typedef __attribute__((ext_vector_type(4))) float f32x4;

__device__ __forceinline__ float ftanh(float x) {
    float ax = fabsf(x);
    float e = __expf(-2.0f * ax);
    float t = (1.0f - e) / (1.0f + e);
    return copysignf(t, x);
}

__device__ __forceinline__ unsigned short f2b(float f) {
    union { float f; unsigned u; } v; v.f = f;
    unsigned r = (v.u + 0x7FFF + ((v.u >> 16) & 1)) >> 16;
    return (unsigned short)r;
}

__device__ __forceinline__ float b2f_hi(unsigned u) {   // high 16 bits as bf16
    union { unsigned u; float f; } v; v.u = u & 0xFFFF0000u;
    return v.f;
}
__device__ __forceinline__ float b2f_lo(unsigned u) {   // low 16 bits as bf16
    union { unsigned u; float f; } v; v.u = u << 16;
    return v.f;
}

// ---------------- setup: bf16 weight transposes + fp32 fw1T ----------------
__global__ void k_setup(const float* __restrict__ fw0, const float* __restrict__ fw1,
                        unsigned short* __restrict__ fw0Tb, unsigned short* __restrict__ fw0b,
                        float* __restrict__ fw1T, unsigned short* __restrict__ fw1Tb) {
    int idx = blockIdx.x * 256 + threadIdx.x;
    if (idx < NTYPES * FHD * DD) {           // fw0Tb [t][o][d] <- fw0[t][d][o]
        int t = idx / (FHD * DD);
        int r = idx % (FHD * DD);
        int o = r / DD, d = r % DD;
        fw0Tb[(long)t * 256 * DD + (long)o * DD + d] =
            f2b(fw0[(long)t * DD * FHD + (long)d * FHD + o]);
    }
    if (idx < NTYPES * DD * 256) {           // fw0b [t][d][kk] (kk>=240 -> 0)
        int t = idx / (DD * 256);
        int r = idx % (DD * 256);
        int d = r / 256, kk = r % 256;
        float v = (kk < FHD) ? fw0[(long)t * DD * FHD + (long)d * FHD + kk] : 0.f;
        fw0b[idx] = f2b(v);
    }
    if (idx < NTYPES * FHD * FHD) {          // fw1T fp32 [t][o][i]
        int t = idx / (FHD * FHD);
        int r = idx % (FHD * FHD);
        int o = r / FHD, i = r % FHD;
        fw1T[idx] = fw1[(long)t * FHD * FHD + (long)i * FHD + o];
    }
    if (idx < NTYPES * FHD * 256) {          // fw1Tb [t][o][kk]
        int t = idx / (FHD * 256);
        int r = idx % (FHD * 256);
        int o = r / 256, kk = r % 256;
        float v = (kk < FHD) ? fw1[(long)t * FHD * FHD + (long)kk * FHD + o] : 0.f;
        fw1Tb[(long)t * 256 * 256 + (long)o * 256 + kk] = f2b(v);
    }
}

// ---------------- table stage 1 ----------------
__global__ __launch_bounds__(256) void k_table_h(
    const float* __restrict__ ew0, const float* __restrict__ eb0,
    const float* __restrict__ ew1, const float* __restrict__ eb1,
    const float* __restrict__ tv)
{
    int idx = blockIdx.x * 256 + threadIdx.x;
    if (idx >= NTYPES * NK) return;
    int t = idx / NK, i = idx % NK;
    float s = S_MIN + (float)i * S_H;

    float h0[E0], t0[E0];
#pragma unroll
    for (int k = 0; k < E0; ++k) {
        float c = eb0[k];
#pragma unroll
        for (int f = 0; f < TFD; ++f) c = fmaf(tv[t * TFD + f], ew0[(1 + f) * E0 + k], c);
        float h = ftanh(fmaf(s, ew0[k], c));
        h0[k] = h;
        t0[k] = (1.f - h * h) * ew0[k];
    }
#pragma unroll 2
    for (int l = 0; l < E1; ++l) {
        float acc = eb1[l], dacc = 0.f;
#pragma unroll
        for (int k = 0; k < E0; ++k) {
            float w = ew1[k * E1 + l];
            acc = fmaf(h0[k], w, acc);
            dacc = fmaf(t0[k], w, dacc);
        }
        float h = ftanh(acc);
        g_th1[(long)idx * E1 + l] = make_float2(h, (1.f - h * h) * dacc);
    }
}

// ---------------- table stage 2 ----------------
__global__ __launch_bounds__(256) void k_table_g(
    const float* __restrict__ ew2, const float* __restrict__ eb2)
{
    long idx = (long)blockIdx.x * 256 + threadIdx.x;
    if (idx >= (long)NTYPES * NK * GD) return;
    int g = idx % GD;
    long ti = idx / GD;
    int i = ti % NK;

    const float2* hv = g_th1 + ti * E1;
    float acc = eb2[g], dacc = 0.f;
#pragma unroll 5
    for (int l = 0; l < E1; ++l) {
        float2 x = hv[l];
        float w = ew2[l * GD + g];
        acc = fmaf(x.x, w, acc);
        dacc = fmaf(x.y, w, dacc);
    }
    float G = ftanh(acc);
    float dv = (1.f - G * G) * dacc;

    float2* f2 = (float2*)g_tab4;
    long e = ti * GD + g;
    f2[2 * e] = make_float2(G, dv);
    if (i > 0) f2[2 * (e - GD) + 1] = make_float2(G, dv);
}

__device__ __forceinline__ const float4* hermite4(float s, int tau,
    float& c00, float& c01, float& c10, float& c11,
    float& d00, float& d10, float& d11)
{
    float x = (s - S_MIN) * S_INVH;
    x = fminf(fmaxf(x, 0.f), (float)(NK - 1) - 1e-3f);
    int i = (int)x;
    float u = x - (float)i;
    float um = 1.f - u;
    c00 = (1.f + 2.f * u) * um * um;
    c01 = u * u * (3.f - 2.f * u);
    c10 = S_H * u * um * um;
    c11 = S_H * u * u * (u - 1.f);
    d00 = (6.f * u * u - 6.f * u) * S_INVH;
    d10 = fmaf(3.f * u, u, fmaf(-4.f, u, 1.f));
    d11 = fmaf(3.f * u, u, -2.f * u);
    return g_tab4 + (long)(tau * NK + i) * GD;
}

// ---------------- K1: lane=channel, item loop per wave; writes dr as bf16 ----------------
__global__ __launch_bounds__(256) void k1_emb(
    const float* __restrict__ Ri,
    unsigned short* __restrict__ drb, float* __restrict__ xa_ws)
{
    __shared__ float4 a4s[JN];
    __shared__ float xar[4 * 400];
    __shared__ float xas[400];

    int tid = threadIdx.x;
    int lane = tid & 63;
    int w = tid >> 6;
    int n = blockIdx.x;

    if (tid < JN) a4s[tid] = ((const float4*)Ri)[(long)n * JN + tid];
    __syncthreads();

    float x0 = 0.f, x1 = 0.f, x2 = 0.f, x3 = 0.f;
    float y0 = 0.f, y1 = 0.f, y2 = 0.f, y3 = 0.f;

    for (int ii = 0; ii < 50; ++ii) {
        int j = w * 50 + ii;
        float4 a = a4s[j];
        int tau = j / MAXNB;
        float c00, c01, c10, c11, d00, d10, d11;
        const float4* row = hermite4(a.x, tau, c00, c01, c10, c11, d00, d10, d11);
        {
            float4 r = row[lane];
            float G = r.x * c00 + r.z * c01 + r.y * c10 + r.w * c11;
            x0 = fmaf(a.x, G, x0); x1 = fmaf(a.y, G, x1);
            x2 = fmaf(a.z, G, x2); x3 = fmaf(a.w, G, x3);
        }
        if (lane < GD - 64) {
            float4 r = row[64 + lane];
            float G = r.x * c00 + r.z * c01 + r.y * c10 + r.w * c11;
            y0 = fmaf(a.x, G, y0); y1 = fmaf(a.y, G, y1);
            y2 = fmaf(a.z, G, y2); y3 = fmaf(a.w, G, y3);
        }
    }

    float* xw = xar + w * 400;
    xw[0 * GD + lane] = x0; xw[1 * GD + lane] = x1;
    xw[2 * GD + lane] = x2; xw[3 * GD + lane] = x3;
    if (lane < GD - 64) {
        xw[0 * GD + 64 + lane] = y0; xw[1 * GD + 64 + lane] = y1;
        xw[2 * GD + 64 + lane] = y2; xw[3 * GD + 64 + lane] = y3;
    }
    __syncthreads();

    for (int i = tid; i < 400; i += 256) {
        float v = (xar[i] + xar[400 + i] + xar[800 + i] + xar[1200 + i]) * INV200;
        xas[i] = v;
        xa_ws[(long)n * 400 + i] = v;
    }
    __syncthreads();

    for (int i = tid; i < DD; i += 256) {
        int gg = i / M2D, m = i % M2D;
        float v = 0.f;
#pragma unroll
        for (int c = 0; c < 4; ++c) v = fmaf(xas[c * GD + gg], xas[c * GD + m], v);
        drb[(long)n * DD + i] = f2b(v);
    }
}

// ---------------- MFMA bf16 GEMM: C = act(A @ BT^T + bias) ----------------
__global__ __launch_bounds__(256) void mgemm(
    const unsigned short* __restrict__ Ab, const unsigned short* __restrict__ BTb,
    const float* __restrict__ biasb, float* __restrict__ Cb, unsigned short* __restrict__ Cbf,
    int M, int N, int K, int Npad,
    long sA, long sBT, long sBias, long sC, long sCbf, int do_tanh)
{
    int t = blockIdx.z;
    const unsigned short* A = Ab + (long)t * sA;
    const unsigned short* BT = BTb + (long)t * sBT;
    const float* bias = biasb ? biasb + (long)t * sBias : nullptr;
    float* C = Cb + (long)t * sC;
    unsigned short* Cb16 = Cbf ? Cbf + (long)t * sCbf : nullptr;

    __shared__ __align__(16) unsigned short As[64 * 72];
    __shared__ __align__(16) unsigned short Bs[64 * 72];

    int tid = threadIdx.x;
    int m0 = blockIdx.x * 64;
    int n0 = blockIdx.y * 64;

    int lane = tid & 63;
    int w = tid >> 6;
    int wm = (w & 1) * 32;
    int wn = (w >> 1) * 32;
    int fm = lane & 15;
    int q = lane >> 4;

    f32x4 acc[2][2] = {};

    int sr = tid >> 2;
    int sc = tid & 3;

    const unsigned short* Ar = A + (long)(m0 + sr) * K + sc * 8;
    const unsigned short* Br = BT + (long)(n0 + sr) * K + sc * 8;
    unsigned short* Asw = As + sr * 72 + sc * 8;
    unsigned short* Bsw = Bs + sr * 72 + sc * 8;

    for (int k0 = 0; k0 < K; k0 += 64) {
        uint4 av0 = *(const uint4*)(Ar + k0);
        uint4 av1 = *(const uint4*)(Ar + k0 + 32);
        uint4 bv0 = *(const uint4*)(Br + k0);
        uint4 bv1 = *(const uint4*)(Br + k0 + 32);
        __syncthreads();
        *(uint4*)(Asw) = av0;
        *(uint4*)(Asw + 32) = av1;
        *(uint4*)(Bsw) = bv0;
        *(uint4*)(Bsw + 32) = bv1;
        __syncthreads();
#pragma unroll
        for (int kk = 0; kk < 64; kk += 32) {
            bf16x8 af0 = *(const bf16x8*)(As + (wm + fm) * 72 + kk + q * 8);
            bf16x8 af1 = *(const bf16x8*)(As + (wm + 16 + fm) * 72 + kk + q * 8);
            bf16x8 bg0 = *(const bf16x8*)(Bs + (wn + fm) * 72 + kk + q * 8);
            bf16x8 bg1 = *(const bf16x8*)(Bs + (wn + 16 + fm) * 72 + kk + q * 8);
            acc[0][0] = __builtin_amdgcn_mfma_f32_16x16x32_bf16(af0, bg0, acc[0][0], 0, 0, 0);
            acc[0][1] = __builtin_amdgcn_mfma_f32_16x16x32_bf16(af0, bg1, acc[0][1], 0, 0, 0);
            acc[1][0] = __builtin_amdgcn_mfma_f32_16x16x32_bf16(af1, bg0, acc[1][0], 0, 0, 0);
            acc[1][1] = __builtin_amdgcn_mfma_f32_16x16x32_bf16(af1, bg1, acc[1][1], 0, 0, 0);
        }
    }

    // C/D layout: col = lane&15, row = q*4 + reg
#pragma unroll
    for (int i = 0; i < 2; ++i) {
#pragma unroll
        for (int j = 0; j < 2; ++j) {
            int col = n0 + wn + j * 16 + fm;
            int rb = m0 + wm + i * 16 + q * 4;
            bool ok = col < N;
            float bv = (bias && ok) ? bias[col] : 0.f;
#pragma unroll
            for (int r = 0; r < 4; ++r) {
                float v = acc[i][j][r] + bv;
                if (do_tanh) v = ftanh(v);
                if (ok) C[(long)(rb + r) * N + col] = v;
                if (Cb16) Cb16[(long)(rb + r) * Npad + col] = ok ? f2b(v) : (unsigned short)0;
            }
        }
    }
}

// ---------------- K3a: per-atom Ei + Etot + dh0g (bf16, K zero-padded) ----------------
__global__ __launch_bounds__(256) void k3a(
    const float* __restrict__ fh0, const float* __restrict__ fh1,
    const float* __restrict__ fw1T, const float* __restrict__ fw2, const float* __restrict__ fb2,
    float* __restrict__ out, unsigned short* __restrict__ dh0gb)
{
    int n = blockIdx.x;
    int t = n / NA;
    int tid = threadIdx.x;
    __shared__ float u1s[FHD];
    __shared__ float red[256];

    float p = 0.f;
    if (tid < FHD) {
        float h1v = fh1[(long)n * FHD + tid];
        float w2v = fw2[t * FHD + tid];
        p = h1v * w2v;
        u1s[tid] = w2v * (1.f - h1v * h1v);
    }
    red[tid] = p;
    __syncthreads();
    for (int off = 128; off > 0; off >>= 1) {
        if (tid < off) red[tid] += red[tid + off];
        __syncthreads();
    }
    if (tid == 0) {
        float e = red[0] + fb2[t];
        out[OUT_EI + n] = e;
        atomicAdd(out, e);
    }
    float val = 0.f;
    if (tid < FHD) {
        const float* wT = fw1T + (long)t * FHD * FHD;
        float acc = 0.f;
        for (int o = 0; o < FHD; ++o) acc = fmaf(u1s[o], wT[o * FHD + tid], acc);
        float h0v = fh0[(long)n * FHD + tid];
        val = acc * (1.f - h0v * h0v);
    }
    dh0gb[(long)n * 256 + tid] = (tid < FHD) ? f2b(val) : (unsigned short)0;
}

// ---------------- K3b: per-atom P, g-major float4 [n][g][c] ----------------
__global__ __launch_bounds__(256) void k3b(
    const float* __restrict__ Q, const float* __restrict__ xa, float* __restrict__ P4)
{
    int n = blockIdx.x;
    int tid = threadIdx.x;
    __shared__ float qs[DD];
    __shared__ float xs[400];
    for (int i = tid; i < DD; i += 256) qs[i] = Q[(long)n * DD + i];
    for (int i = tid; i < 400; i += 256) xs[i] = xa[(long)n * 400 + i];
    __syncthreads();
    for (int i = tid; i < 400; i += 256) {
        int c = i / GD, g = i % GD;
        float acc = 0.f;
        for (int m = 0; m < M2D; ++m) acc = fmaf(qs[g * M2D + m], xs[c * GD + m], acc);
        if (g < M2D) {
            for (int g2 = 0; g2 < GD; ++g2) acc = fmaf(qs[g2 * M2D + g], xs[c * GD + g2], acc);
        }
        P4[((long)n * GD + g) * 4 + c] = acc * INV200;
    }
}

// ---------------- K4: block=atom; basis precomputed per item; packed bf16 G/dG staging ----------------
// Phase 0: per item, compute Hermite basis (7 floats) + table-row offset once -> LDS.
// Staging (per chunk of 20 channels): lane<->flat(item,channel); per element:
// 2 LDS b128 broadcast basis reads + 1 coalesced-ish global float4 + 8 FMA + pack
// (G,dG) as 2xbf16 in one uint. Compute: thread=item, 1 ds_read_b32 + unpack + 8 FMA
// per channel; P4s broadcast. LDS ~29KB -> 5 blocks/CU.
#define KCH 20
#define KST 21
__global__ __launch_bounds__(256) void k4(
    const float* __restrict__ Ri, const float* __restrict__ dfeat,
    const float* __restrict__ ImageDR, const int* __restrict__ list_neigh,
    const float4* __restrict__ P4ws, float* __restrict__ out)
{
    __shared__ float4 a4s[JN];
    __shared__ float4 basA[JN];     // c00,c01,c10,c11
    __shared__ float4 basB[JN];     // d00,d10,d11,-
    __shared__ int rowoff[JN];      // (tau*NK + knot)*GD
    __shared__ float4 P4s[GD];
    __shared__ unsigned Pk[JN * KST];
    __shared__ float facc3[3];
    __shared__ float vacc[6];

    int tid = threadIdx.x;
    int lane = tid & 63;
    int n = blockIdx.x;

    if (tid < JN) {
        float4 a = ((const float4*)Ri)[(long)n * JN + tid];
        a4s[tid] = a;
        int tau = tid / MAXNB;
        float c00, c01, c10, c11, d00, d10, d11;
        const float4* row = hermite4(a.x, tau, c00, c01, c10, c11, d00, d10, d11);
        basA[tid] = make_float4(c00, c01, c10, c11);
        basB[tid] = make_float4(d00, d10, d11, 0.f);
        rowoff[tid] = (int)(row - g_tab4);
    }
    if (tid < GD) P4s[tid] = P4ws[(long)n * GD + tid];
    if (tid < 3) facc3[tid] = 0.f;
    if (tid < 6) vacc[tid] = 0.f;
    __syncthreads();

    float M10 = 0.f, M11 = 0.f, M12 = 0.f, M13 = 0.f;
    float M20 = 0.f, M21 = 0.f, M22 = 0.f, M23 = 0.f;

    for (int cc = 0; cc < 5; ++cc) {
        int g0 = cc * KCH;
#pragma unroll 2
        for (int f = tid; f < JN * KCH; f += 256) {
            int j = f / KCH;
            int ch = f - j * KCH;
            float4 ba = basA[j];
            float4 bb = basB[j];
            float4 r = g_tab4[rowoff[j] + g0 + ch];
            float G = r.x * ba.x + r.z * ba.y + r.y * ba.z + r.w * ba.w;
            float Dv = (r.x - r.z) * bb.x + r.y * bb.y + r.w * bb.z;
            Pk[j * KST + ch] = ((unsigned)f2b(G) << 16) | (unsigned)f2b(Dv);
        }
        __syncthreads();
        if (tid < JN) {
            const unsigned* pr = Pk + tid * KST;
#pragma unroll
            for (int gl = 0; gl < KCH; ++gl) {
                unsigned u = pr[gl];
                float G = b2f_hi(u);
                float Dv = b2f_lo(u);
                float4 p = P4s[g0 + gl];
                M10 = fmaf(p.x, G, M10); M11 = fmaf(p.y, G, M11);
                M12 = fmaf(p.z, G, M12); M13 = fmaf(p.w, G, M13);
                M20 = fmaf(p.x, Dv, M20); M21 = fmaf(p.y, Dv, M21);
                M22 = fmaf(p.z, Dv, M22); M23 = fmaf(p.w, Dv, M23);
            }
        }
        __syncthreads();
    }

    float v00 = 0.f, v01 = 0.f, v02 = 0.f, v11 = 0.f, v12 = 0.f, v22 = 0.f;
    if (tid < JN) {
        long item = (long)n * JN + tid;
        float4 a = a4s[tid];
        float ds = a.x * M20 + a.y * M21 + a.z * M22 + a.w * M23;
        float dEda0 = M10 + ds, dEda1 = M11, dEda2 = M12, dEda3 = M13;

        const float4* dfp = (const float4*)(dfeat + item * 12);
        float4 q0 = dfp[0], q1 = dfp[1], q2 = dfp[2];
        float dEdx0 = dEda0 * q0.x + dEda1 * q0.w + dEda2 * q1.z + dEda3 * q2.y;
        float dEdx1 = dEda0 * q0.y + dEda1 * q1.x + dEda2 * q1.w + dEda3 * q2.z;
        float dEdx2 = dEda0 * q0.z + dEda1 * q1.y + dEda2 * q2.x + dEda3 * q2.w;

        atomicAdd(&facc3[0], dEdx0);
        atomicAdd(&facc3[1], dEdx1);
        atomicAdd(&facc3[2], dEdx2);

        int ln = list_neigh[item];
        if (ln > 0) {
            int ii2 = ln - 1;
            if (ii2 > NATOMS - 1) ii2 = NATOMS - 1;
            atomicAdd(&out[OUT_F + ii2 * 3 + 0], dEdx0);
            atomicAdd(&out[OUT_F + ii2 * 3 + 1], dEdx1);
            atomicAdd(&out[OUT_F + ii2 * 3 + 2], dEdx2);
            const float* im = ImageDR + item * 3;
            v00 = im[0] * dEdx0; v01 = im[0] * dEdx1; v02 = im[0] * dEdx2;
            v11 = im[1] * dEdx1; v12 = im[1] * dEdx2; v22 = im[2] * dEdx2;
        }
    }

#pragma unroll
    for (int mask = 32; mask > 0; mask >>= 1) {
        v00 += __shfl_xor(v00, mask);
        v01 += __shfl_xor(v01, mask);
        v02 += __shfl_xor(v02, mask);
        v11 += __shfl_xor(v11, mask);
        v12 += __shfl_xor(v12, mask);
        v22 += __shfl_xor(v22, mask);
    }
    if (lane == 0) {
        atomicAdd(&vacc[0], v00);
        atomicAdd(&vacc[1], v01);
        atomicAdd(&vacc[2], v02);
        atomicAdd(&vacc[3], v11);
        atomicAdd(&vacc[4], v12);
        atomicAdd(&vacc[5], v22);
    }
    __syncthreads();
    if (tid < 3) atomicAdd(&out[OUT_F + n * 3 + tid], -facc3[tid]);
    if (tid < 9) {
        const int vmap[9] = {0, 1, 2, 1, 3, 4, 2, 4, 5};
        atomicAdd(&out[OUT_V + tid], vacc[vmap[tid]]);
    }
}

extern "C" void kernel_launch(void* const* d_in, const int* in_sizes, int n_in,
                              void* d_out, int out_size, void* d_ws, size_t ws_size,
                              hipStream_t stream) {
    const float* Ri = (const float*)d_in[0];
    const float* dfeat = (const float*)d_in[1];
    const float* ImageDR = (const float*)d_in[2];
    const float* tv = (const float*)d_in[3];
    const float* ew0 = (const float*)d_in[4];
    const float* eb0 = (const float*)d_in[5];
    const float* ew1 = (const float*)d_in[6];
    const float* eb1 = (const float*)d_in[7];
    const float* ew2 = (const float*)d_in[8];
    const float* eb2 = (const float*)d_in[9];
    const float* fw0 = (const float*)d_in[10];
    const float* fb0 = (const float*)d_in[11];
    const float* fw1 = (const float*)d_in[12];
    const float* fb1 = (const float*)d_in[13];
    const float* fw2 = (const float*)d_in[14];
    const float* fb2 = (const float*)d_in[15];
    const int* list_neigh = (const int*)d_in[16];

    float* out = (float*)d_out;
    float* ws = (float*)d_ws;
    float* Q = ws + WS_Q;
    float* fw1T = ws + WS_FW1T;
    unsigned short* drb = (unsigned short*)(ws + WS_DRB);
    float* xa = ws + WS_XA;
    float* P = ws + WS_P;
    float* fh0 = ws + WS_FH0;
    float* fh1 = ws + WS_FH1;
    unsigned short* dh0gb = (unsigned short*)(ws + WS_DH0GB);
    unsigned short* fh0b = (unsigned short*)(ws + WS_FH0B);
    unsigned short* fw0Tb = (unsigned short*)(ws + WS_FW0TB);
    unsigned short* fw0b = (unsigned short*)(ws + WS_FW0B);
    unsigned short* fw1Tb = (unsigned short*)(ws + WS_FW1TB);

    hipMemsetAsync(d_out, 0, (size_t)out_size * sizeof(float), stream);

    k_setup<<<(NTYPES * DD * 256 + 255) / 256, 256, 0, stream>>>(
        fw0, fw1, fw0Tb, fw0b, fw1T, fw1Tb);
    k_table_h<<<(NTYPES * NK + 255) / 256, 256, 0, stream>>>(ew0, eb0, ew1, eb1, tv);
    k_table_g<<<(NTYPES * NK * GD + 255) / 256, 256, 0, stream>>>(ew2, eb2);

    k1_emb<<<NATOMS, 256, 0, stream>>>(Ri, drb, xa);

    // fh0 = tanh(dr @ fw0 + fb0)  [+ bf16 copy for next GEMM]
    mgemm<<<dim3(32, 4, 2), 256, 0, stream>>>(
        drb, fw0Tb, fb0, fh0, fh0b,
        2048, 240, 1600, 256,
        2048L * 1600, 256L * 1600, 240L, 2048L * 240, 2048L * 256, 1);
    // fh1 = tanh(fh0 @ fw1 + fb1)
    mgemm<<<dim3(32, 4, 2), 256, 0, stream>>>(
        fh0b, fw1Tb, fb1, fh1, nullptr,
        2048, 240, 256, 0,
        2048L * 256, 256L * 256, 240L, 2048L * 240, 0L, 1);

    k3a<<<NATOMS, 256, 0, stream>>>(fh0, fh1, fw1T, fw2, fb2, out, dh0gb);

    // Q = dh0g @ fw0^T
    mgemm<<<dim3(32, 25, 2), 256, 0, stream>>>(
        dh0gb, fw0b, nullptr, Q, nullptr,
        2048, 1600, 256, 0,
        2048L * 256, 1600L * 256, 0L, 2048L * 1600, 0L, 0);

    k3b<<<NATOMS, 256, 0, stream>>>(Q, xa, P);

    k4<<<NATOMS, 256, 0, stream>>>(Ri, dfeat, ImageDR, list_neigh,
        (const float4*)P, out);
}